// Round 1
// baseline (5903.185 us; speedup 1.0000x reference)
//
#include <hip/hip_runtime.h>
#include <math.h>

#define HID 256

// ---------- edge weight MLP: ew = sigmoid(relu([id_emb|pos_emb] @ W1 + b1) @ W2 + b2)
// also accumulates deg[dst] += ew  (deg must be zeroed first)
__global__ void k_edge(const int* __restrict__ eid, const int* __restrict__ epos,
                       const float* __restrict__ id_emb, const float* __restrict__ pos_emb,
                       const float* __restrict__ w1, const float* __restrict__ b1,
                       const float* __restrict__ w2, const float* __restrict__ b2,
                       const int* __restrict__ ei, float* __restrict__ ew,
                       float* __restrict__ deg, int E) {
    __shared__ float sW1[100];
    __shared__ float sB1[10];
    __shared__ float sW2[10];
    __shared__ float sB2;
    int t = threadIdx.x;
    if (t < 100) sW1[t] = w1[t];
    if (t < 10) { sB1[t] = b1[t]; sW2[t] = w2[t]; }
    if (t == 0) sB2 = b2[0];
    __syncthreads();
    int e = blockIdx.x * blockDim.x + t;
    if (e >= E) return;
    int id = eid[e];
    int p  = epos[e];
    float f[10];
#pragma unroll
    for (int i = 0; i < 8; i++) f[i] = id_emb[id * 8 + i];
    f[8] = pos_emb[p * 2 + 0];
    f[9] = pos_emb[p * 2 + 1];
    float acc = sB2;
#pragma unroll
    for (int j = 0; j < 10; j++) {
        float h = sB1[j];
#pragma unroll
        for (int i = 0; i < 10; i++) h += f[i] * sW1[i * 10 + j];
        h = fmaxf(h, 0.f);
        acc += h * sW2[j];
    }
    float w = 1.f / (1.f + expf(-acc));
    ew[e] = w;
    int dst = ei[E + e];
    atomicAdd(&deg[dst], w);
}

// ---------- dinv = 1/sqrt(deg+1)   (in place)
__global__ void k_dinv(float* __restrict__ deg, int N) {
    int i = blockIdx.x * blockDim.x + threadIdx.x;
    if (i < N) deg[i] = 1.f / sqrtf(deg[i] + 1.f);
}

// ---------- xw1 = node_features[N,3] @ conv1_w[3,256]
__global__ void k_xw1(const float* __restrict__ nf, const float* __restrict__ W,
                      float* __restrict__ XW, int N) {
    int n = blockIdx.x;
    int c = threadIdx.x;
    if (n >= N) return;
    float x0 = nf[n * 3 + 0], x1 = nf[n * 3 + 1], x2 = nf[n * 3 + 2];
    XW[n * HID + c] = x0 * W[c] + x1 * W[HID + c] + x2 * W[2 * HID + c];
}

// ---------- scatter: AGG[dst] += dinv[src]*ew[e]*dinv[dst] * XW[src]
// one wave (64 lanes) per edge, 4 floats per lane
__global__ void k_scatter(const int* __restrict__ ei, const float* __restrict__ ew,
                          const float* __restrict__ dinv, const float* __restrict__ XW,
                          float* __restrict__ AGG, int E) {
    int wave = threadIdx.x >> 6;
    int lane = threadIdx.x & 63;
    int e = blockIdx.x * 4 + wave;
    if (e >= E) return;
    int src = ei[e];
    int dst = ei[E + e];
    float norm = dinv[src] * ew[e] * dinv[dst];
    const float4 v = *(const float4*)(XW + src * HID + lane * 4);
    float* a = AGG + dst * HID + lane * 4;
    atomicAdd(a + 0, norm * v.x);
    atomicAdd(a + 1, norm * v.y);
    atomicAdd(a + 2, norm * v.z);
    atomicAdd(a + 3, norm * v.w);
}

// ---------- x = relu(AGG + dinv[n]^2 * XW + b)   (in place in AGG)
__global__ void k_fin(float* __restrict__ AGG, const float* __restrict__ XW,
                      const float* __restrict__ dinv, const float* __restrict__ b, int N) {
    int n = blockIdx.x;
    int c = threadIdx.x;
    if (n >= N) return;
    float d = dinv[n];
    int idx = n * HID + c;
    AGG[idx] = fmaxf(AGG[idx] + d * d * XW[idx] + b[c], 0.f);
}

// ---------- Y[N,256] = X[N,256] @ W[256,256]   (8 rows per block, 256 threads)
__global__ void k_gemm256(const float* __restrict__ X, const float* __restrict__ W,
                          float* __restrict__ Y, int N) {
    __shared__ float xs[8][HID];
    int c = threadIdx.x;
    int n0 = blockIdx.x * 8;
#pragma unroll
    for (int r = 0; r < 8; r++) {
        int n = n0 + r;
        xs[r][c] = (n < N) ? X[n * HID + c] : 0.f;
    }
    __syncthreads();
    float acc[8];
#pragma unroll
    for (int r = 0; r < 8; r++) acc[r] = 0.f;
    for (int k = 0; k < HID; k++) {
        float wk = W[k * HID + c];
#pragma unroll
        for (int r = 0; r < 8; r++) acc[r] += xs[r][k] * wk;
    }
#pragma unroll
    for (int r = 0; r < 8; r++) {
        int n = n0 + r;
        if (n < N) Y[n * HID + c] = acc[r];
    }
}

// ---------- column sums of X[N,256] -> gsum[256] via atomics (gsum zeroed first)
__global__ void k_colsum(const float* __restrict__ X, float* __restrict__ gsum, int N) {
    int c = threadIdx.x;
    int n0 = blockIdx.x * 64;
    float s = 0.f;
    for (int r = 0; r < 64; r++) {
        int n = n0 + r;
        if (n < N) s += X[n * HID + c];
    }
    atomicAdd(&gsum[c], s);
}

// ---------- gbias[c] = actor_b1[c] + sum_j g[j]*actor_w1[256+j][c]
__global__ void k_gbias(const float* __restrict__ gsum, const float* __restrict__ aw1,
                        const float* __restrict__ ab1, float* __restrict__ gbias, float invN) {
    int c = threadIdx.x;
    float s = ab1[c];
    for (int j = 0; j < HID; j++) s += gsum[j] * invN * aw1[(HID + j) * HID + c];
    gbias[c] = s;
}

// ---------- critic head on pooled = [g, g]; writes sv_out[0]
__global__ void k_critic(const float* __restrict__ gsum,
                         const float* __restrict__ cw1, const float* __restrict__ cb1,
                         const float* __restrict__ cw2, const float* __restrict__ cb2,
                         const float* __restrict__ cw3, const float* __restrict__ cb3,
                         float* __restrict__ sv_out, float invN) {
    __shared__ float p[2 * HID];
    __shared__ float c1[2 * HID];
    __shared__ float c2[HID];
    int t = threadIdx.x;  // 512 threads
    p[t] = gsum[t & (HID - 1)] * invN;
    __syncthreads();
    float s = cb1[t];
    for (int i = 0; i < 2 * HID; i++) s += p[i] * cw1[i * 2 * HID + t];
    c1[t] = fmaxf(s, 0.f);
    __syncthreads();
    if (t < HID) {
        float s2 = cb2[t];
        for (int i = 0; i < 2 * HID; i++) s2 += c1[i] * cw2[i * HID + t];
        c2[t] = fmaxf(s2, 0.f) * cw3[t];
    }
    __syncthreads();
    for (int st = HID / 2; st > 0; st >>= 1) {
        if (t < st) c2[t] += c2[t + st];
        __syncthreads();
    }
    if (t == 0) sv_out[0] = c2[0] + cb3[0];
}

// ---------- actor: logits[n] = relu(x2[n] @ aw1_top + gbias) @ aw2 + ab2
__global__ void k_actor(const float* __restrict__ X, const float* __restrict__ aw1,
                        const float* __restrict__ gbias, const float* __restrict__ aw2,
                        const float* __restrict__ ab2, float* __restrict__ out, int N) {
    __shared__ float xs[8][HID];
    __shared__ float red[HID];
    int c = threadIdx.x;
    int n0 = blockIdx.x * 8;
#pragma unroll
    for (int r = 0; r < 8; r++) {
        int n = n0 + r;
        xs[r][c] = (n < N) ? X[n * HID + c] : 0.f;
    }
    __syncthreads();
    float acc[8];
#pragma unroll
    for (int r = 0; r < 8; r++) acc[r] = 0.f;
    for (int k = 0; k < HID; k++) {
        float wk = aw1[k * HID + c];  // top half rows of actor_w1
#pragma unroll
        for (int r = 0; r < 8; r++) acc[r] += xs[r][k] * wk;
    }
    float w2c = aw2[c];
    float b2 = ab2[0];
    float gb = gbias[c];
    for (int r = 0; r < 8; r++) {
        red[c] = fmaxf(acc[r] + gb, 0.f) * w2c;
        __syncthreads();
        for (int st = HID / 2; st > 0; st >>= 1) {
            if (c < st) red[c] += red[c + st];
            __syncthreads();
        }
        if (c == 0 && n0 + r < N) out[n0 + r] = red[0] + b2;
        __syncthreads();
    }
}

extern "C" void kernel_launch(void* const* d_in, const int* in_sizes, int n_in,
                              void* d_out, int out_size, void* d_ws, size_t ws_size,
                              hipStream_t stream) {
    const float* nf      = (const float*)d_in[0];
    const int*   ei      = (const int*)d_in[1];
    const int*   eid     = (const int*)d_in[2];
    const int*   epos    = (const int*)d_in[3];
    const float* id_emb  = (const float*)d_in[4];
    const float* pos_emb = (const float*)d_in[5];
    const float* ew_w1   = (const float*)d_in[6];
    const float* ew_b1   = (const float*)d_in[7];
    const float* ew_w2   = (const float*)d_in[8];
    const float* ew_b2   = (const float*)d_in[9];
    const float* c1w     = (const float*)d_in[10];
    const float* c1b     = (const float*)d_in[11];
    const float* c2w     = (const float*)d_in[12];
    const float* c2b     = (const float*)d_in[13];
    const float* aw1     = (const float*)d_in[14];
    const float* ab1     = (const float*)d_in[15];
    const float* aw2     = (const float*)d_in[16];
    const float* ab2     = (const float*)d_in[17];
    const float* cw1     = (const float*)d_in[18];
    const float* cb1     = (const float*)d_in[19];
    const float* cw2     = (const float*)d_in[20];
    const float* cb2     = (const float*)d_in[21];
    const float* cw3     = (const float*)d_in[22];
    const float* cb3     = (const float*)d_in[23];

    int N = in_sizes[0] / 3;
    int E = in_sizes[2];
    float invN = 1.f / (float)N;

    float* ws = (float*)d_ws;
    float* A     = ws;                    // xw buffer  [N,256]
    float* B     = A + (size_t)N * HID;   // agg/x buffer [N,256]
    float* ew    = B + (size_t)N * HID;   // [E]
    float* deg   = ew + E;                // [N], becomes dinv
    float* gsum  = deg + N;               // [256]
    float* gbias = gsum + HID;            // [256]

    float* out = (float*)d_out;  // [N] logits + [1] state value

    // --- edge MLP + degree
    hipMemsetAsync(deg, 0, (size_t)N * sizeof(float), stream);
    k_edge<<<(E + 255) / 256, 256, 0, stream>>>(eid, epos, id_emb, pos_emb,
                                                ew_w1, ew_b1, ew_w2, ew_b2, ei, ew, deg, E);
    k_dinv<<<(N + 255) / 256, 256, 0, stream>>>(deg, N);

    // --- layer 1
    k_xw1<<<N, HID, 0, stream>>>(nf, c1w, A, N);
    hipMemsetAsync(B, 0, (size_t)N * HID * sizeof(float), stream);
    k_scatter<<<(E + 3) / 4, 256, 0, stream>>>(ei, ew, deg, A, B, E);
    k_fin<<<N, HID, 0, stream>>>(B, A, deg, c1b, N);   // B = x1

    // --- layer 2
    k_gemm256<<<(N + 7) / 8, HID, 0, stream>>>(B, c2w, A, N);  // A = x1 @ conv2_w
    hipMemsetAsync(B, 0, (size_t)N * HID * sizeof(float), stream);
    k_scatter<<<(E + 3) / 4, 256, 0, stream>>>(ei, ew, deg, A, B, E);
    k_fin<<<N, HID, 0, stream>>>(B, A, deg, c2b, N);   // B = x2

    // --- pooling
    hipMemsetAsync(gsum, 0, HID * sizeof(float), stream);
    k_colsum<<<(N + 63) / 64, HID, 0, stream>>>(B, gsum, N);
    k_gbias<<<1, HID, 0, stream>>>(gsum, aw1, ab1, gbias, invN);

    // --- critic (writes out[N])
    k_critic<<<1, 2 * HID, 0, stream>>>(gsum, cw1, cb1, cw2, cb2, cw3, cb3, out + N, invN);

    // --- actor (writes out[0..N))
    k_actor<<<(N + 7) / 8, HID, 0, stream>>>(B, aw1, gbias, aw2, ab2, out, N);
}

// Round 2
// 1045.618 us; speedup vs baseline: 5.6456x; 5.6456x over previous
//
#include <hip/hip_runtime.h>
#include <math.h>

#define HID 256

// ---------- edge weight MLP: ew = sigmoid(relu([id_emb|pos_emb] @ W1 + b1) @ W2 + b2)
// also accumulates deg[dst] += ew (float) and cnt[dst]++ (int) — both zeroed first
__global__ void k_edge(const int* __restrict__ eid, const int* __restrict__ epos,
                       const float* __restrict__ id_emb, const float* __restrict__ pos_emb,
                       const float* __restrict__ w1, const float* __restrict__ b1,
                       const float* __restrict__ w2, const float* __restrict__ b2,
                       const int* __restrict__ ei, float* __restrict__ ew,
                       float* __restrict__ deg, int* __restrict__ cnt, int E) {
    __shared__ float sW1[100];
    __shared__ float sB1[10];
    __shared__ float sW2[10];
    __shared__ float sB2;
    int t = threadIdx.x;
    if (t < 100) sW1[t] = w1[t];
    if (t < 10) { sB1[t] = b1[t]; sW2[t] = w2[t]; }
    if (t == 0) sB2 = b2[0];
    __syncthreads();
    int e = blockIdx.x * blockDim.x + t;
    if (e >= E) return;
    int id = eid[e];
    int p  = epos[e];
    float f[10];
#pragma unroll
    for (int i = 0; i < 8; i++) f[i] = id_emb[id * 8 + i];
    f[8] = pos_emb[p * 2 + 0];
    f[9] = pos_emb[p * 2 + 1];
    float acc = sB2;
#pragma unroll
    for (int j = 0; j < 10; j++) {
        float h = sB1[j];
#pragma unroll
        for (int i = 0; i < 10; i++) h += f[i] * sW1[i * 10 + j];
        h = fmaxf(h, 0.f);
        acc += h * sW2[j];
    }
    float w = 1.f / (1.f + expf(-acc));
    ew[e] = w;
    int dst = ei[E + e];
    atomicAdd(&deg[dst], w);
    atomicAdd(&cnt[dst], 1);
}

// ---------- dinv = 1/sqrt(deg+1)   (in place)
__global__ void k_dinv(float* __restrict__ deg, int N) {
    int i = blockIdx.x * blockDim.x + threadIdx.x;
    if (i < N) deg[i] = 1.f / sqrtf(deg[i] + 1.f);
}

// ---------- exclusive prefix scan of cnt[N] -> row_ptr[N+1]  (single block, 1024 thr)
__global__ void k_scan(const int* __restrict__ cnt, int* __restrict__ row_ptr, int N) {
    __shared__ int sums[1024];
    int t = threadIdx.x;
    int per = (N + 1023) / 1024;
    int start = t * per;
    int end = min(start + per, N);
    int s = 0;
    for (int i = start; i < end; i++) s += cnt[i];
    sums[t] = s;
    __syncthreads();
    for (int off = 1; off < 1024; off <<= 1) {
        int v = (t >= off) ? sums[t - off] : 0;
        __syncthreads();
        if (t >= off) sums[t] += v;
        __syncthreads();
    }
    int excl = (t == 0) ? 0 : sums[t - 1];
    for (int i = start; i < end; i++) { row_ptr[i] = excl; excl += cnt[i]; }
    if (t == 1023) row_ptr[N] = excl;
}

// ---------- fill CSR: slot = cursor[dst]++; csr_src[slot]=src; csr_norm[slot]=dinv[src]*ew*dinv[dst]
__global__ void k_fill(const int* __restrict__ ei, const float* __restrict__ ew,
                       const float* __restrict__ dinv, int* __restrict__ cursor,
                       int* __restrict__ csr_src, float* __restrict__ csr_norm, int E) {
    int e = blockIdx.x * blockDim.x + threadIdx.x;
    if (e >= E) return;
    int src = ei[e];
    int dst = ei[E + e];
    int slot = atomicAdd(&cursor[dst], 1);
    csr_src[slot] = src;
    csr_norm[slot] = dinv[src] * ew[e] * dinv[dst];
}

// ---------- xw1 = node_features[N,3] @ conv1_w[3,256]
__global__ void k_xw1(const float* __restrict__ nf, const float* __restrict__ W,
                      float* __restrict__ XW, int N) {
    int n = blockIdx.x;
    int c = threadIdx.x;
    if (n >= N) return;
    float x0 = nf[n * 3 + 0], x1 = nf[n * 3 + 1], x2 = nf[n * 3 + 2];
    XW[n * HID + c] = x0 * W[c] + x1 * W[HID + c] + x2 * W[2 * HID + c];
}

// ---------- gather + self-loop + bias + relu:
// out[n,c] = relu( sum_{i in row(n)} csr_norm[i]*XW[csr_src[i],c] + dinv[n]^2*XW[n,c] + b[c] )
__global__ void k_gather(const int* __restrict__ row_ptr, const int* __restrict__ csr_src,
                         const float* __restrict__ csr_norm, const float* __restrict__ XW,
                         const float* __restrict__ dinv, const float* __restrict__ b,
                         float* __restrict__ out, int N) {
    int n = blockIdx.x;
    int c = threadIdx.x;
    int s = row_ptr[n];
    int e = row_ptr[n + 1];
    float acc = 0.f;
    for (int i = s; i < e; i++) {
        int src = csr_src[i];
        float w = csr_norm[i];
        acc += w * XW[src * HID + c];
    }
    float d = dinv[n];
    out[n * HID + c] = fmaxf(acc + d * d * XW[n * HID + c] + b[c], 0.f);
}

// ---------- Y[N,256] = X[N,256] @ W[256,256]   (8 rows per block, 256 threads)
__global__ void k_gemm256(const float* __restrict__ X, const float* __restrict__ W,
                          float* __restrict__ Y, int N) {
    __shared__ float xs[8][HID];
    int c = threadIdx.x;
    int n0 = blockIdx.x * 8;
#pragma unroll
    for (int r = 0; r < 8; r++) {
        int n = n0 + r;
        xs[r][c] = (n < N) ? X[n * HID + c] : 0.f;
    }
    __syncthreads();
    float acc[8];
#pragma unroll
    for (int r = 0; r < 8; r++) acc[r] = 0.f;
    for (int k = 0; k < HID; k++) {
        float wk = W[k * HID + c];
#pragma unroll
        for (int r = 0; r < 8; r++) acc[r] += xs[r][k] * wk;
    }
#pragma unroll
    for (int r = 0; r < 8; r++) {
        int n = n0 + r;
        if (n < N) Y[n * HID + c] = acc[r];
    }
}

// ---------- column sums of X[N,256] -> gsum[256] via atomics (gsum zeroed first)
__global__ void k_colsum(const float* __restrict__ X, float* __restrict__ gsum, int N) {
    int c = threadIdx.x;
    int n0 = blockIdx.x * 64;
    float s = 0.f;
    for (int r = 0; r < 64; r++) {
        int n = n0 + r;
        if (n < N) s += X[n * HID + c];
    }
    atomicAdd(&gsum[c], s);
}

// ---------- gbias[c] = actor_b1[c] + sum_j g[j]*actor_w1[256+j][c]
__global__ void k_gbias(const float* __restrict__ gsum, const float* __restrict__ aw1,
                        const float* __restrict__ ab1, float* __restrict__ gbias, float invN) {
    int c = threadIdx.x;
    float s = ab1[c];
    for (int j = 0; j < HID; j++) s += gsum[j] * invN * aw1[(HID + j) * HID + c];
    gbias[c] = s;
}

// ---------- critic head on pooled = [g, g]; writes sv_out[0]
__global__ void k_critic(const float* __restrict__ gsum,
                         const float* __restrict__ cw1, const float* __restrict__ cb1,
                         const float* __restrict__ cw2, const float* __restrict__ cb2,
                         const float* __restrict__ cw3, const float* __restrict__ cb3,
                         float* __restrict__ sv_out, float invN) {
    __shared__ float p[2 * HID];
    __shared__ float c1[2 * HID];
    __shared__ float c2[HID];
    int t = threadIdx.x;  // 512 threads
    p[t] = gsum[t & (HID - 1)] * invN;
    __syncthreads();
    float s = cb1[t];
    for (int i = 0; i < 2 * HID; i++) s += p[i] * cw1[i * 2 * HID + t];
    c1[t] = fmaxf(s, 0.f);
    __syncthreads();
    if (t < HID) {
        float s2 = cb2[t];
        for (int i = 0; i < 2 * HID; i++) s2 += c1[i] * cw2[i * HID + t];
        c2[t] = fmaxf(s2, 0.f) * cw3[t];
    }
    __syncthreads();
    for (int st = HID / 2; st > 0; st >>= 1) {
        if (t < st) c2[t] += c2[t + st];
        __syncthreads();
    }
    if (t == 0) sv_out[0] = c2[0] + cb3[0];
}

// ---------- actor: logits[n] = relu(x2[n] @ aw1_top + gbias) @ aw2 + ab2
__global__ void k_actor(const float* __restrict__ X, const float* __restrict__ aw1,
                        const float* __restrict__ gbias, const float* __restrict__ aw2,
                        const float* __restrict__ ab2, float* __restrict__ out, int N) {
    __shared__ float xs[8][HID];
    __shared__ float red[HID];
    int c = threadIdx.x;
    int n0 = blockIdx.x * 8;
#pragma unroll
    for (int r = 0; r < 8; r++) {
        int n = n0 + r;
        xs[r][c] = (n < N) ? X[n * HID + c] : 0.f;
    }
    __syncthreads();
    float acc[8];
#pragma unroll
    for (int r = 0; r < 8; r++) acc[r] = 0.f;
    for (int k = 0; k < HID; k++) {
        float wk = aw1[k * HID + c];  // top half rows of actor_w1
#pragma unroll
        for (int r = 0; r < 8; r++) acc[r] += xs[r][k] * wk;
    }
    float w2c = aw2[c];
    float b2 = ab2[0];
    float gb = gbias[c];
    for (int r = 0; r < 8; r++) {
        red[c] = fmaxf(acc[r] + gb, 0.f) * w2c;
        __syncthreads();
        for (int st = HID / 2; st > 0; st >>= 1) {
            if (c < st) red[c] += red[c + st];
            __syncthreads();
        }
        if (c == 0 && n0 + r < N) out[n0 + r] = red[0] + b2;
        __syncthreads();
    }
}

extern "C" void kernel_launch(void* const* d_in, const int* in_sizes, int n_in,
                              void* d_out, int out_size, void* d_ws, size_t ws_size,
                              hipStream_t stream) {
    const float* nf      = (const float*)d_in[0];
    const int*   ei      = (const int*)d_in[1];
    const int*   eid     = (const int*)d_in[2];
    const int*   epos    = (const int*)d_in[3];
    const float* id_emb  = (const float*)d_in[4];
    const float* pos_emb = (const float*)d_in[5];
    const float* ew_w1   = (const float*)d_in[6];
    const float* ew_b1   = (const float*)d_in[7];
    const float* ew_w2   = (const float*)d_in[8];
    const float* ew_b2   = (const float*)d_in[9];
    const float* c1w     = (const float*)d_in[10];
    const float* c1b     = (const float*)d_in[11];
    const float* c2w     = (const float*)d_in[12];
    const float* c2b     = (const float*)d_in[13];
    const float* aw1     = (const float*)d_in[14];
    const float* ab1     = (const float*)d_in[15];
    const float* aw2     = (const float*)d_in[16];
    const float* ab2     = (const float*)d_in[17];
    const float* cw1     = (const float*)d_in[18];
    const float* cb1     = (const float*)d_in[19];
    const float* cw2     = (const float*)d_in[20];
    const float* cb2     = (const float*)d_in[21];
    const float* cw3     = (const float*)d_in[22];
    const float* cb3     = (const float*)d_in[23];

    int N = in_sizes[0] / 3;
    int E = in_sizes[2];
    float invN = 1.f / (float)N;

    char* ws = (char*)d_ws;
    float* A        = (float*)ws;                         ws += (size_t)N * HID * 4;
    float* B        = (float*)ws;                         ws += (size_t)N * HID * 4;
    float* ew       = (float*)ws;                         ws += (size_t)E * 4;
    float* csr_norm = (float*)ws;                         ws += (size_t)E * 4;
    int*   csr_src  = (int*)ws;                           ws += (size_t)E * 4;
    float* deg      = (float*)ws;                         ws += (size_t)N * 4;
    int*   cnt      = (int*)ws;                           ws += (size_t)N * 4;
    int*   row_ptr  = (int*)ws;                           ws += (size_t)(N + 1) * 4;
    int*   cursor   = (int*)ws;                           ws += (size_t)N * 4;
    float* gsum     = (float*)ws;                         ws += HID * 4;
    float* gbias    = (float*)ws;                         ws += HID * 4;

    float* out = (float*)d_out;  // [N] logits + [1] state value

    // --- edge MLP + degree + histogram
    hipMemsetAsync(deg, 0, (size_t)N * sizeof(float), stream);
    hipMemsetAsync(cnt, 0, (size_t)N * sizeof(int), stream);
    k_edge<<<(E + 255) / 256, 256, 0, stream>>>(eid, epos, id_emb, pos_emb,
                                                ew_w1, ew_b1, ew_w2, ew_b2, ei, ew, deg, cnt, E);
    k_dinv<<<(N + 255) / 256, 256, 0, stream>>>(deg, N);

    // --- CSR build
    k_scan<<<1, 1024, 0, stream>>>(cnt, row_ptr, N);
    hipMemcpyAsync(cursor, row_ptr, (size_t)N * sizeof(int), hipMemcpyDeviceToDevice, stream);
    k_fill<<<(E + 255) / 256, 256, 0, stream>>>(ei, ew, deg, cursor, csr_src, csr_norm, E);

    // --- layer 1
    k_xw1<<<N, HID, 0, stream>>>(nf, c1w, A, N);
    k_gather<<<N, HID, 0, stream>>>(row_ptr, csr_src, csr_norm, A, deg, c1b, B, N);  // B = x1

    // --- layer 2
    k_gemm256<<<(N + 7) / 8, HID, 0, stream>>>(B, c2w, A, N);  // A = x1 @ conv2_w
    k_gather<<<N, HID, 0, stream>>>(row_ptr, csr_src, csr_norm, A, deg, c2b, B, N);  // B = x2

    // --- pooling
    hipMemsetAsync(gsum, 0, HID * sizeof(float), stream);
    k_colsum<<<(N + 63) / 64, HID, 0, stream>>>(B, gsum, N);
    k_gbias<<<1, HID, 0, stream>>>(gsum, aw1, ab1, gbias, invN);

    // --- critic (writes out[N])
    k_critic<<<1, 2 * HID, 0, stream>>>(gsum, cw1, cb1, cw2, cb2, cw3, cb3, out + N, invN);

    // --- actor (writes out[0..N))
    k_actor<<<(N + 7) / 8, HID, 0, stream>>>(B, aw1, gbias, aw2, ab2, out, N);
}

// Round 3
// 838.417 us; speedup vs baseline: 7.0409x; 1.2471x over previous
//
#include <hip/hip_runtime.h>
#include <math.h>

#define HID 256

// ---------- edge weight MLP: ew = sigmoid(relu([id_emb|pos_emb] @ W1 + b1) @ W2 + b2)
// also accumulates deg[dst] += ew (float) and cnt[dst]++ (int) — both zeroed first
__global__ void k_edge(const int* __restrict__ eid, const int* __restrict__ epos,
                       const float* __restrict__ id_emb, const float* __restrict__ pos_emb,
                       const float* __restrict__ w1, const float* __restrict__ b1,
                       const float* __restrict__ w2, const float* __restrict__ b2,
                       const int* __restrict__ ei, float* __restrict__ ew,
                       float* __restrict__ deg, int* __restrict__ cnt, int E) {
    __shared__ float sW1[100];
    __shared__ float sB1[10];
    __shared__ float sW2[10];
    __shared__ float sB2;
    int t = threadIdx.x;
    if (t < 100) sW1[t] = w1[t];
    if (t < 10) { sB1[t] = b1[t]; sW2[t] = w2[t]; }
    if (t == 0) sB2 = b2[0];
    __syncthreads();
    int e = blockIdx.x * blockDim.x + t;
    if (e >= E) return;
    int id = eid[e];
    int p  = epos[e];
    const float4* ide = (const float4*)(id_emb + (size_t)id * 8);
    float4 fa = ide[0], fb = ide[1];
    float f[10];
    f[0] = fa.x; f[1] = fa.y; f[2] = fa.z; f[3] = fa.w;
    f[4] = fb.x; f[5] = fb.y; f[6] = fb.z; f[7] = fb.w;
    f[8] = pos_emb[p * 2 + 0];
    f[9] = pos_emb[p * 2 + 1];
    float acc = sB2;
#pragma unroll
    for (int j = 0; j < 10; j++) {
        float h = sB1[j];
#pragma unroll
        for (int i = 0; i < 10; i++) h += f[i] * sW1[i * 10 + j];
        h = fmaxf(h, 0.f);
        acc += h * sW2[j];
    }
    float w = 1.f / (1.f + expf(-acc));
    ew[e] = w;
    int dst = ei[E + e];
    atomicAdd(&deg[dst], w);
    atomicAdd(&cnt[dst], 1);
}

// ---------- dinv = 1/sqrt(deg+1)   (in place)
__global__ void k_dinv(float* __restrict__ deg, int N) {
    int i = blockIdx.x * blockDim.x + threadIdx.x;
    if (i < N) deg[i] = 1.f / sqrtf(deg[i] + 1.f);
}

// ---------- exclusive prefix scan of cnt[N] -> row_ptr[N+1]  (single block, 1024 thr)
__global__ void k_scan(const int* __restrict__ cnt, int* __restrict__ row_ptr, int N) {
    __shared__ int sums[1024];
    int t = threadIdx.x;
    int per = (N + 1023) / 1024;
    int start = t * per;
    int end = min(start + per, N);
    int s = 0;
    for (int i = start; i < end; i++) s += cnt[i];
    sums[t] = s;
    __syncthreads();
    for (int off = 1; off < 1024; off <<= 1) {
        int v = (t >= off) ? sums[t - off] : 0;
        __syncthreads();
        if (t >= off) sums[t] += v;
        __syncthreads();
    }
    int excl = (t == 0) ? 0 : sums[t - 1];
    for (int i = start; i < end; i++) { row_ptr[i] = excl; excl += cnt[i]; }
    if (t == 1023) row_ptr[N] = excl;
}

// ---------- fill CSR: slot = cursor[dst]++; csr[slot] = {src, bitcast(norm)}
__global__ void k_fill(const int* __restrict__ ei, const float* __restrict__ ew,
                       const float* __restrict__ dinv, int* __restrict__ cursor,
                       int2* __restrict__ csr, int E) {
    int e = blockIdx.x * blockDim.x + threadIdx.x;
    if (e >= E) return;
    int src = ei[e];
    int dst = ei[E + e];
    int slot = atomicAdd(&cursor[dst], 1);
    float norm = dinv[src] * ew[e] * dinv[dst];
    csr[slot] = make_int2(src, __float_as_int(norm));
}

// ---------- xw1 = node_features[N,3] @ conv1_w[3,256]
__global__ void k_xw1(const float* __restrict__ nf, const float* __restrict__ W,
                      float* __restrict__ XW, int N) {
    int n = blockIdx.x;
    int c = threadIdx.x;
    if (n >= N) return;
    float x0 = nf[n * 3 + 0], x1 = nf[n * 3 + 1], x2 = nf[n * 3 + 2];
    XW[n * HID + c] = x0 * W[c] + x1 * W[HID + c] + x2 * W[2 * HID + c];
}

// ---------- gather + self-loop + bias + relu (one wave per dst node, float4/lane)
__global__ void k_gather(const int* __restrict__ row_ptr, const int2* __restrict__ csr,
                         const float* __restrict__ XW, const float* __restrict__ dinv,
                         const float* __restrict__ b, float* __restrict__ out, int N) {
    int lane = threadIdx.x & 63;
    int wv = threadIdx.x >> 6;
    int n = blockIdx.x * 4 + wv;
    if (n >= N) return;
    int s = row_ptr[n];
    int e = row_ptr[n + 1];
    float4 acc = make_float4(0.f, 0.f, 0.f, 0.f);
    for (int i = s; i < e; i++) {
        int2 sn = csr[i];
        int src = sn.x;
        float w = __int_as_float(sn.y);
        const float4 v = *(const float4*)(XW + (size_t)src * HID + lane * 4);
        acc.x = fmaf(w, v.x, acc.x);
        acc.y = fmaf(w, v.y, acc.y);
        acc.z = fmaf(w, v.z, acc.z);
        acc.w = fmaf(w, v.w, acc.w);
    }
    float d = dinv[n];
    float dd = d * d;
    const float4 xv = *(const float4*)(XW + (size_t)n * HID + lane * 4);
    const float4 bv = *(const float4*)(b + lane * 4);
    float4 o;
    o.x = fmaxf(acc.x + dd * xv.x + bv.x, 0.f);
    o.y = fmaxf(acc.y + dd * xv.y + bv.y, 0.f);
    o.z = fmaxf(acc.z + dd * xv.z + bv.z, 0.f);
    o.w = fmaxf(acc.w + dd * xv.w + bv.w, 0.f);
    *(float4*)(out + (size_t)n * HID + lane * 4) = o;
}

// ================= register-tiled f32 GEMM: Y[N,256] = X[N,256] @ W[256,256]
// block = 256 thr, 32 rows; thread (tx=tid&63, ty=tid>>6) -> rows ty*8+0..7, cols 4tx..4tx+3
#define XS_STRIDE 36
__device__ __forceinline__ void gemm_tile_load(const float* __restrict__ X, float* xsT,
                                               int n0, int N, int tid) {
    int r = tid >> 3;        // 0..31
    int c8 = tid & 7;        // 0..7
    int n = n0 + r;
#pragma unroll
    for (int j = 0; j < 8; j++) {
        int c4 = c8 + 8 * j;  // 0..63
        float4 v = make_float4(0.f, 0.f, 0.f, 0.f);
        if (n < N) v = *(const float4*)(X + (size_t)n * HID + 4 * c4);
        int col = 4 * c4;
        xsT[(col + 0) * XS_STRIDE + r] = v.x;
        xsT[(col + 1) * XS_STRIDE + r] = v.y;
        xsT[(col + 2) * XS_STRIDE + r] = v.z;
        xsT[(col + 3) * XS_STRIDE + r] = v.w;
    }
}

__global__ __launch_bounds__(256) void k_gemm256(const float* __restrict__ X,
                                                 const float* __restrict__ W,
                                                 float* __restrict__ Y, int N) {
    __shared__ __align__(16) float xsT[HID * XS_STRIDE];
    int tid = threadIdx.x;
    int n0 = blockIdx.x * 32;
    gemm_tile_load(X, xsT, n0, N, tid);
    __syncthreads();
    int tx = tid & 63;
    int ty = tid >> 6;
    float4 acc[8];
#pragma unroll
    for (int i = 0; i < 8; i++) acc[i] = make_float4(0.f, 0.f, 0.f, 0.f);
    const float* Wc = W + 4 * tx;
    const float* xbase = &xsT[ty * 8];
    for (int k = 0; k < HID; k++) {
        float4 w4 = *(const float4*)(Wc + (size_t)k * HID);
        const float* xp = xbase + k * XS_STRIDE;
        float4 xa = *(const float4*)xp;
        float4 xb = *(const float4*)(xp + 4);
        float xv[8];
        *(float4*)&xv[0] = xa;
        *(float4*)&xv[4] = xb;
#pragma unroll
        for (int i = 0; i < 8; i++) {
            acc[i].x = fmaf(xv[i], w4.x, acc[i].x);
            acc[i].y = fmaf(xv[i], w4.y, acc[i].y);
            acc[i].z = fmaf(xv[i], w4.z, acc[i].z);
            acc[i].w = fmaf(xv[i], w4.w, acc[i].w);
        }
    }
#pragma unroll
    for (int i = 0; i < 8; i++) {
        int n = n0 + ty * 8 + i;
        if (n < N) *(float4*)(Y + (size_t)n * HID + 4 * tx) = acc[i];
    }
}

// ---------- actor fused: logits[n] = relu(x2[n] @ aw1_top + gbias) @ aw2 + ab2
__global__ __launch_bounds__(256) void k_actor(const float* __restrict__ X,
                                               const float* __restrict__ aw1,
                                               const float* __restrict__ gbias,
                                               const float* __restrict__ aw2,
                                               const float* __restrict__ ab2,
                                               float* __restrict__ out, int N) {
    __shared__ __align__(16) float xsT[HID * XS_STRIDE];
    int tid = threadIdx.x;
    int n0 = blockIdx.x * 32;
    gemm_tile_load(X, xsT, n0, N, tid);
    __syncthreads();
    int tx = tid & 63;
    int ty = tid >> 6;
    float4 acc[8];
#pragma unroll
    for (int i = 0; i < 8; i++) acc[i] = make_float4(0.f, 0.f, 0.f, 0.f);
    const float* Wc = aw1 + 4 * tx;
    const float* xbase = &xsT[ty * 8];
    for (int k = 0; k < HID; k++) {
        float4 w4 = *(const float4*)(Wc + (size_t)k * HID);
        const float* xp = xbase + k * XS_STRIDE;
        float4 xa = *(const float4*)xp;
        float4 xb = *(const float4*)(xp + 4);
        float xv[8];
        *(float4*)&xv[0] = xa;
        *(float4*)&xv[4] = xb;
#pragma unroll
        for (int i = 0; i < 8; i++) {
            acc[i].x = fmaf(xv[i], w4.x, acc[i].x);
            acc[i].y = fmaf(xv[i], w4.y, acc[i].y);
            acc[i].z = fmaf(xv[i], w4.z, acc[i].z);
            acc[i].w = fmaf(xv[i], w4.w, acc[i].w);
        }
    }
    float4 gb = *(const float4*)(gbias + 4 * tx);
    float4 w2 = *(const float4*)(aw2 + 4 * tx);
    float b2 = ab2[0];
#pragma unroll
    for (int i = 0; i < 8; i++) {
        float v = fmaxf(acc[i].x + gb.x, 0.f) * w2.x
                + fmaxf(acc[i].y + gb.y, 0.f) * w2.y
                + fmaxf(acc[i].z + gb.z, 0.f) * w2.z
                + fmaxf(acc[i].w + gb.w, 0.f) * w2.w;
#pragma unroll
        for (int off = 32; off > 0; off >>= 1) v += __shfl_down(v, off, 64);
        int n = n0 + ty * 8 + i;
        if (tx == 0 && n < N) out[n] = v + b2;
    }
}

// ---------- column sums of X[N,256] -> gsum[256] via atomics (gsum zeroed first)
__global__ void k_colsum(const float* __restrict__ X, float* __restrict__ gsum, int N) {
    int c = threadIdx.x;
    int n0 = blockIdx.x * 64;
    float s = 0.f;
    for (int r = 0; r < 64; r++) {
        int n = n0 + r;
        if (n < N) s += X[n * HID + c];
    }
    atomicAdd(&gsum[c], s);
}

// ---------- gbias[c] = actor_b1[c] + sum_j g[j]*actor_w1[256+j][c]
__global__ void k_gbias(const float* __restrict__ gsum, const float* __restrict__ aw1,
                        const float* __restrict__ ab1, float* __restrict__ gbias, float invN) {
    int c = threadIdx.x;
    float s = ab1[c];
    for (int j = 0; j < HID; j++) s += gsum[j] * invN * aw1[(HID + j) * HID + c];
    gbias[c] = s;
}

// ---------- critic head on pooled = [g, g]; writes sv_out[0]
__global__ void k_critic(const float* __restrict__ gsum,
                         const float* __restrict__ cw1, const float* __restrict__ cb1,
                         const float* __restrict__ cw2, const float* __restrict__ cb2,
                         const float* __restrict__ cw3, const float* __restrict__ cb3,
                         float* __restrict__ sv_out, float invN) {
    __shared__ float p[2 * HID];
    __shared__ float c1[2 * HID];
    __shared__ float c2[HID];
    int t = threadIdx.x;  // 512 threads
    p[t] = gsum[t & (HID - 1)] * invN;
    __syncthreads();
    float s = cb1[t];
    for (int i = 0; i < 2 * HID; i++) s += p[i] * cw1[i * 2 * HID + t];
    c1[t] = fmaxf(s, 0.f);
    __syncthreads();
    if (t < HID) {
        float s2 = cb2[t];
        for (int i = 0; i < 2 * HID; i++) s2 += c1[i] * cw2[i * HID + t];
        c2[t] = fmaxf(s2, 0.f) * cw3[t];
    }
    __syncthreads();
    for (int st = HID / 2; st > 0; st >>= 1) {
        if (t < st) c2[t] += c2[t + st];
        __syncthreads();
    }
    if (t == 0) sv_out[0] = c2[0] + cb3[0];
}

extern "C" void kernel_launch(void* const* d_in, const int* in_sizes, int n_in,
                              void* d_out, int out_size, void* d_ws, size_t ws_size,
                              hipStream_t stream) {
    const float* nf      = (const float*)d_in[0];
    const int*   ei      = (const int*)d_in[1];
    const int*   eid     = (const int*)d_in[2];
    const int*   epos    = (const int*)d_in[3];
    const float* id_emb  = (const float*)d_in[4];
    const float* pos_emb = (const float*)d_in[5];
    const float* ew_w1   = (const float*)d_in[6];
    const float* ew_b1   = (const float*)d_in[7];
    const float* ew_w2   = (const float*)d_in[8];
    const float* ew_b2   = (const float*)d_in[9];
    const float* c1w     = (const float*)d_in[10];
    const float* c1b     = (const float*)d_in[11];
    const float* c2w     = (const float*)d_in[12];
    const float* c2b     = (const float*)d_in[13];
    const float* aw1     = (const float*)d_in[14];
    const float* ab1     = (const float*)d_in[15];
    const float* aw2     = (const float*)d_in[16];
    const float* ab2     = (const float*)d_in[17];
    const float* cw1     = (const float*)d_in[18];
    const float* cb1     = (const float*)d_in[19];
    const float* cw2     = (const float*)d_in[20];
    const float* cb2     = (const float*)d_in[21];
    const float* cw3     = (const float*)d_in[22];
    const float* cb3     = (const float*)d_in[23];

    int N = in_sizes[0] / 3;
    int E = in_sizes[2];
    float invN = 1.f / (float)N;

    char* ws = (char*)d_ws;
    float* A        = (float*)ws;                         ws += (size_t)N * HID * 4;
    float* B        = (float*)ws;                         ws += (size_t)N * HID * 4;
    float* ew       = (float*)ws;                         ws += (size_t)E * 4;
    int2*  csr      = (int2*)ws;                          ws += (size_t)E * 8;
    float* deg      = (float*)ws;                         ws += (size_t)N * 4;
    int*   cnt      = (int*)ws;                           ws += (size_t)N * 4;
    int*   row_ptr  = (int*)ws;                           ws += (size_t)(N + 1) * 4;
    int*   cursor   = (int*)ws;                           ws += (size_t)N * 4;
    float* gsum     = (float*)ws;                         ws += HID * 4;
    float* gbias    = (float*)ws;                         ws += HID * 4;

    float* out = (float*)d_out;  // [N] logits + [1] state value

    // --- edge MLP + degree + histogram
    hipMemsetAsync(deg, 0, (size_t)N * sizeof(float), stream);
    hipMemsetAsync(cnt, 0, (size_t)N * sizeof(int), stream);
    k_edge<<<(E + 255) / 256, 256, 0, stream>>>(eid, epos, id_emb, pos_emb,
                                                ew_w1, ew_b1, ew_w2, ew_b2, ei, ew, deg, cnt, E);
    k_dinv<<<(N + 255) / 256, 256, 0, stream>>>(deg, N);

    // --- CSR build
    k_scan<<<1, 1024, 0, stream>>>(cnt, row_ptr, N);
    hipMemcpyAsync(cursor, row_ptr, (size_t)N * sizeof(int), hipMemcpyDeviceToDevice, stream);
    k_fill<<<(E + 255) / 256, 256, 0, stream>>>(ei, ew, deg, cursor, csr, E);

    // --- layer 1
    k_xw1<<<N, HID, 0, stream>>>(nf, c1w, A, N);
    k_gather<<<(N + 3) / 4, 256, 0, stream>>>(row_ptr, csr, A, deg, c1b, B, N);  // B = x1

    // --- layer 2
    k_gemm256<<<(N + 31) / 32, 256, 0, stream>>>(B, c2w, A, N);  // A = x1 @ conv2_w
    k_gather<<<(N + 3) / 4, 256, 0, stream>>>(row_ptr, csr, A, deg, c2b, B, N);  // B = x2

    // --- pooling
    hipMemsetAsync(gsum, 0, HID * sizeof(float), stream);
    k_colsum<<<(N + 63) / 64, HID, 0, stream>>>(B, gsum, N);
    k_gbias<<<1, HID, 0, stream>>>(gsum, aw1, ab1, gbias, invN);

    // --- critic (writes out[N])
    k_critic<<<1, 2 * HID, 0, stream>>>(gsum, cw1, cb1, cw2, cb2, cw3, cb3, out + N, invN);

    // --- actor (writes out[0..N))
    k_actor<<<(N + 31) / 32, 256, 0, stream>>>(B, aw1, gbias, aw2, ab2, out, N);
}

// Round 4
// 743.872 us; speedup vs baseline: 7.9358x; 1.1271x over previous
//
#include <hip/hip_runtime.h>
#include <math.h>

#define HID 256

// ---------- edge weight MLP: ew = sigmoid(relu([id_emb|pos_emb] @ W1 + b1) @ W2 + b2)
// also accumulates deg[dst] += ew (float) and cnt[dst]++ (int) — both zeroed first
__global__ void k_edge(const int* __restrict__ eid, const int* __restrict__ epos,
                       const float* __restrict__ id_emb, const float* __restrict__ pos_emb,
                       const float* __restrict__ w1, const float* __restrict__ b1,
                       const float* __restrict__ w2, const float* __restrict__ b2,
                       const int* __restrict__ ei, float* __restrict__ ew,
                       float* __restrict__ deg, int* __restrict__ cnt, int E) {
    __shared__ float sW1[100];
    __shared__ float sB1[10];
    __shared__ float sW2[10];
    __shared__ float sB2;
    int t = threadIdx.x;
    if (t < 100) sW1[t] = w1[t];
    if (t < 10) { sB1[t] = b1[t]; sW2[t] = w2[t]; }
    if (t == 0) sB2 = b2[0];
    __syncthreads();
    int e = blockIdx.x * blockDim.x + t;
    if (e >= E) return;
    int id = eid[e];
    int p  = epos[e];
    const float4* ide = (const float4*)(id_emb + (size_t)id * 8);
    float4 fa = ide[0], fb = ide[1];
    float f[10];
    f[0] = fa.x; f[1] = fa.y; f[2] = fa.z; f[3] = fa.w;
    f[4] = fb.x; f[5] = fb.y; f[6] = fb.z; f[7] = fb.w;
    f[8] = pos_emb[p * 2 + 0];
    f[9] = pos_emb[p * 2 + 1];
    float acc = sB2;
#pragma unroll
    for (int j = 0; j < 10; j++) {
        float h = sB1[j];
#pragma unroll
        for (int i = 0; i < 10; i++) h += f[i] * sW1[i * 10 + j];
        h = fmaxf(h, 0.f);
        acc += h * sW2[j];
    }
    float w = 1.f / (1.f + expf(-acc));
    ew[e] = w;
    int dst = ei[E + e];
    atomicAdd(&deg[dst], w);
    atomicAdd(&cnt[dst], 1);
}

// ---------- dinv = 1/sqrt(deg+1)   (in place)
__global__ void k_dinv(float* __restrict__ deg, int N) {
    int i = blockIdx.x * blockDim.x + threadIdx.x;
    if (i < N) deg[i] = 1.f / sqrtf(deg[i] + 1.f);
}

// ---------- exclusive prefix scan of cnt[N] -> row_ptr[N+1] AND cursor[N]
__global__ void k_scan(const int* __restrict__ cnt, int* __restrict__ row_ptr,
                       int* __restrict__ cursor, int N) {
    __shared__ int sums[1024];
    int t = threadIdx.x;
    int per = (N + 1023) / 1024;
    int start = t * per;
    int end = min(start + per, N);
    int s = 0;
    for (int i = start; i < end; i++) s += cnt[i];
    sums[t] = s;
    __syncthreads();
    for (int off = 1; off < 1024; off <<= 1) {
        int v = (t >= off) ? sums[t - off] : 0;
        __syncthreads();
        if (t >= off) sums[t] += v;
        __syncthreads();
    }
    int excl = (t == 0) ? 0 : sums[t - 1];
    for (int i = start; i < end; i++) {
        row_ptr[i] = excl;
        cursor[i] = excl;
        excl += cnt[i];
    }
    if (t == 1023) row_ptr[N] = excl;
}

// ---------- fill CSR: slot = cursor[dst]++; csr[slot] = {src, bitcast(norm)}
__global__ void k_fill(const int* __restrict__ ei, const float* __restrict__ ew,
                       const float* __restrict__ dinv, int* __restrict__ cursor,
                       int2* __restrict__ csr, int E) {
    int e = blockIdx.x * blockDim.x + threadIdx.x;
    if (e >= E) return;
    int src = ei[e];
    int dst = ei[E + e];
    int slot = atomicAdd(&cursor[dst], 1);
    float norm = dinv[src] * ew[e] * dinv[dst];
    csr[slot] = make_int2(src, __float_as_int(norm));
}

// ---------- layer-1 aggregation on RAW features (3 floats/node), one thread per node
// T3[n] = sum_e norm*nf[src] + dinv[n]^2 * nf[n]   (stored as float4, pad=0)
__global__ void k_agg3(const int* __restrict__ row_ptr, const int2* __restrict__ csr,
                       const float* __restrict__ nf, const float* __restrict__ dinv,
                       float4* __restrict__ T3, int N) {
    int n = blockIdx.x * blockDim.x + threadIdx.x;
    if (n >= N) return;
    int s = row_ptr[n];
    int e = row_ptr[n + 1];
    float ax = 0.f, ay = 0.f, az = 0.f;
    for (int i = s; i < e; i++) {
        int2 sn = csr[i];
        int src = sn.x;
        float w = __int_as_float(sn.y);
        ax = fmaf(w, nf[src * 3 + 0], ax);
        ay = fmaf(w, nf[src * 3 + 1], ay);
        az = fmaf(w, nf[src * 3 + 2], az);
    }
    float d = dinv[n];
    float dd = d * d;
    ax = fmaf(dd, nf[n * 3 + 0], ax);
    ay = fmaf(dd, nf[n * 3 + 1], ay);
    az = fmaf(dd, nf[n * 3 + 2], az);
    T3[n] = make_float4(ax, ay, az, 0.f);
}

// ---------- x1 = relu(T3 @ conv1_w + b1)
__global__ void k_x1(const float4* __restrict__ T3, const float* __restrict__ W,
                     const float* __restrict__ b, float* __restrict__ X1, int N) {
    int n = blockIdx.x;
    int c = threadIdx.x;
    if (n >= N) return;
    float4 t = T3[n];
    float v = t.x * W[c] + t.y * W[HID + c] + t.z * W[2 * HID + c] + b[c];
    X1[n * HID + c] = fmaxf(v, 0.f);
}

// ---------- linear gather (256-wide): T[n] = sum norm*X[src] + dinv[n]^2*X[n]
__global__ void k_gatherlin(const int* __restrict__ row_ptr, const int2* __restrict__ csr,
                            const float* __restrict__ X, const float* __restrict__ dinv,
                            float* __restrict__ out, int N) {
    int lane = threadIdx.x & 63;
    int wv = threadIdx.x >> 6;
    int n = blockIdx.x * 4 + wv;
    if (n >= N) return;
    int s = row_ptr[n];
    int e = row_ptr[n + 1];
    float4 acc = make_float4(0.f, 0.f, 0.f, 0.f);
    for (int i = s; i < e; i++) {
        int2 sn = csr[i];
        int src = sn.x;
        float w = __int_as_float(sn.y);
        const float4 v = *(const float4*)(X + (size_t)src * HID + lane * 4);
        acc.x = fmaf(w, v.x, acc.x);
        acc.y = fmaf(w, v.y, acc.y);
        acc.z = fmaf(w, v.z, acc.z);
        acc.w = fmaf(w, v.w, acc.w);
    }
    float d = dinv[n];
    float dd = d * d;
    const float4 xv = *(const float4*)(X + (size_t)n * HID + lane * 4);
    float4 o;
    o.x = fmaf(dd, xv.x, acc.x);
    o.y = fmaf(dd, xv.y, acc.y);
    o.z = fmaf(dd, xv.z, acc.z);
    o.w = fmaf(dd, xv.w, acc.w);
    *(float4*)(out + (size_t)n * HID + lane * 4) = o;
}

// ================= register-tiled f32 GEMM with fused bias+relu:
// Y[N,256] = relu(X[N,256] @ W[256,256] + b)
// block = 256 thr, 32 rows; thread (tx=tid&63, ty=tid>>6) -> rows ty*8+0..7, cols 4tx..4tx+3
#define XS_STRIDE 36
__device__ __forceinline__ void gemm_tile_load(const float* __restrict__ X, float* xsT,
                                               int n0, int N, int tid) {
    int r = tid >> 3;        // 0..31
    int c8 = tid & 7;        // 0..7
    int n = n0 + r;
#pragma unroll
    for (int j = 0; j < 8; j++) {
        int c4 = c8 + 8 * j;  // 0..63
        float4 v = make_float4(0.f, 0.f, 0.f, 0.f);
        if (n < N) v = *(const float4*)(X + (size_t)n * HID + 4 * c4);
        int col = 4 * c4;
        xsT[(col + 0) * XS_STRIDE + r] = v.x;
        xsT[(col + 1) * XS_STRIDE + r] = v.y;
        xsT[(col + 2) * XS_STRIDE + r] = v.z;
        xsT[(col + 3) * XS_STRIDE + r] = v.w;
    }
}

__global__ __launch_bounds__(256) void k_gemm256(const float* __restrict__ X,
                                                 const float* __restrict__ W,
                                                 const float* __restrict__ b,
                                                 float* __restrict__ Y, int N) {
    __shared__ __align__(16) float xsT[HID * XS_STRIDE];
    int tid = threadIdx.x;
    int n0 = blockIdx.x * 32;
    gemm_tile_load(X, xsT, n0, N, tid);
    __syncthreads();
    int tx = tid & 63;
    int ty = tid >> 6;
    float4 acc[8];
#pragma unroll
    for (int i = 0; i < 8; i++) acc[i] = make_float4(0.f, 0.f, 0.f, 0.f);
    const float* Wc = W + 4 * tx;
    const float* xbase = &xsT[ty * 8];
    for (int k = 0; k < HID; k++) {
        float4 w4 = *(const float4*)(Wc + (size_t)k * HID);
        const float* xp = xbase + k * XS_STRIDE;
        float4 xa = *(const float4*)xp;
        float4 xb = *(const float4*)(xp + 4);
        float xv[8];
        *(float4*)&xv[0] = xa;
        *(float4*)&xv[4] = xb;
#pragma unroll
        for (int i = 0; i < 8; i++) {
            acc[i].x = fmaf(xv[i], w4.x, acc[i].x);
            acc[i].y = fmaf(xv[i], w4.y, acc[i].y);
            acc[i].z = fmaf(xv[i], w4.z, acc[i].z);
            acc[i].w = fmaf(xv[i], w4.w, acc[i].w);
        }
    }
    float4 bv = *(const float4*)(b + 4 * tx);
#pragma unroll
    for (int i = 0; i < 8; i++) {
        int n = n0 + ty * 8 + i;
        if (n < N) {
            float4 o;
            o.x = fmaxf(acc[i].x + bv.x, 0.f);
            o.y = fmaxf(acc[i].y + bv.y, 0.f);
            o.z = fmaxf(acc[i].z + bv.z, 0.f);
            o.w = fmaxf(acc[i].w + bv.w, 0.f);
            *(float4*)(Y + (size_t)n * HID + 4 * tx) = o;
        }
    }
}

// ---------- actor fused: logits[n] = relu(x2[n] @ aw1_top + gbias) @ aw2 + ab2
__global__ __launch_bounds__(256) void k_actor(const float* __restrict__ X,
                                               const float* __restrict__ aw1,
                                               const float* __restrict__ gbias,
                                               const float* __restrict__ aw2,
                                               const float* __restrict__ ab2,
                                               float* __restrict__ out, int N) {
    __shared__ __align__(16) float xsT[HID * XS_STRIDE];
    int tid = threadIdx.x;
    int n0 = blockIdx.x * 32;
    gemm_tile_load(X, xsT, n0, N, tid);
    __syncthreads();
    int tx = tid & 63;
    int ty = tid >> 6;
    float4 acc[8];
#pragma unroll
    for (int i = 0; i < 8; i++) acc[i] = make_float4(0.f, 0.f, 0.f, 0.f);
    const float* Wc = aw1 + 4 * tx;
    const float* xbase = &xsT[ty * 8];
    for (int k = 0; k < HID; k++) {
        float4 w4 = *(const float4*)(Wc + (size_t)k * HID);
        const float* xp = xbase + k * XS_STRIDE;
        float4 xa = *(const float4*)xp;
        float4 xb = *(const float4*)(xp + 4);
        float xv[8];
        *(float4*)&xv[0] = xa;
        *(float4*)&xv[4] = xb;
#pragma unroll
        for (int i = 0; i < 8; i++) {
            acc[i].x = fmaf(xv[i], w4.x, acc[i].x);
            acc[i].y = fmaf(xv[i], w4.y, acc[i].y);
            acc[i].z = fmaf(xv[i], w4.z, acc[i].z);
            acc[i].w = fmaf(xv[i], w4.w, acc[i].w);
        }
    }
    float4 gb = *(const float4*)(gbias + 4 * tx);
    float4 w2 = *(const float4*)(aw2 + 4 * tx);
    float b2 = ab2[0];
#pragma unroll
    for (int i = 0; i < 8; i++) {
        float v = fmaxf(acc[i].x + gb.x, 0.f) * w2.x
                + fmaxf(acc[i].y + gb.y, 0.f) * w2.y
                + fmaxf(acc[i].z + gb.z, 0.f) * w2.z
                + fmaxf(acc[i].w + gb.w, 0.f) * w2.w;
#pragma unroll
        for (int off = 32; off > 0; off >>= 1) v += __shfl_down(v, off, 64);
        int n = n0 + ty * 8 + i;
        if (tx == 0 && n < N) out[n] = v + b2;
    }
}

// ---------- column sums of X[N,256] -> gsum[256] via atomics (gsum zeroed first)
__global__ void k_colsum(const float* __restrict__ X, float* __restrict__ gsum, int N) {
    int c = threadIdx.x;
    int n0 = blockIdx.x * 64;
    float s = 0.f;
    for (int r = 0; r < 64; r++) {
        int n = n0 + r;
        if (n < N) s += X[n * HID + c];
    }
    atomicAdd(&gsum[c], s);
}

// ---------- gbias[c] = actor_b1[c] + sum_j g[j]*actor_w1[256+j][c]
__global__ void k_gbias(const float* __restrict__ gsum, const float* __restrict__ aw1,
                        const float* __restrict__ ab1, float* __restrict__ gbias, float invN) {
    int c = threadIdx.x;
    float s = ab1[c];
    for (int j = 0; j < HID; j++) s += gsum[j] * invN * aw1[(HID + j) * HID + c];
    gbias[c] = s;
}

// ---------- critic head on pooled = [g, g]; writes sv_out[0]
__global__ void k_critic(const float* __restrict__ gsum,
                         const float* __restrict__ cw1, const float* __restrict__ cb1,
                         const float* __restrict__ cw2, const float* __restrict__ cb2,
                         const float* __restrict__ cw3, const float* __restrict__ cb3,
                         float* __restrict__ sv_out, float invN) {
    __shared__ float p[2 * HID];
    __shared__ float c1[2 * HID];
    __shared__ float c2[HID];
    int t = threadIdx.x;  // 512 threads
    p[t] = gsum[t & (HID - 1)] * invN;
    __syncthreads();
    float s = cb1[t];
    for (int i = 0; i < 2 * HID; i++) s += p[i] * cw1[i * 2 * HID + t];
    c1[t] = fmaxf(s, 0.f);
    __syncthreads();
    if (t < HID) {
        float s2 = cb2[t];
        for (int i = 0; i < 2 * HID; i++) s2 += c1[i] * cw2[i * HID + t];
        c2[t] = fmaxf(s2, 0.f) * cw3[t];
    }
    __syncthreads();
    for (int st = HID / 2; st > 0; st >>= 1) {
        if (t < st) c2[t] += c2[t + st];
        __syncthreads();
    }
    if (t == 0) sv_out[0] = c2[0] + cb3[0];
}

extern "C" void kernel_launch(void* const* d_in, const int* in_sizes, int n_in,
                              void* d_out, int out_size, void* d_ws, size_t ws_size,
                              hipStream_t stream) {
    const float* nf      = (const float*)d_in[0];
    const int*   ei      = (const int*)d_in[1];
    const int*   eid     = (const int*)d_in[2];
    const int*   epos    = (const int*)d_in[3];
    const float* id_emb  = (const float*)d_in[4];
    const float* pos_emb = (const float*)d_in[5];
    const float* ew_w1   = (const float*)d_in[6];
    const float* ew_b1   = (const float*)d_in[7];
    const float* ew_w2   = (const float*)d_in[8];
    const float* ew_b2   = (const float*)d_in[9];
    const float* c1w     = (const float*)d_in[10];
    const float* c1b     = (const float*)d_in[11];
    const float* c2w     = (const float*)d_in[12];
    const float* c2b     = (const float*)d_in[13];
    const float* aw1     = (const float*)d_in[14];
    const float* ab1     = (const float*)d_in[15];
    const float* aw2     = (const float*)d_in[16];
    const float* ab2     = (const float*)d_in[17];
    const float* cw1     = (const float*)d_in[18];
    const float* cb1     = (const float*)d_in[19];
    const float* cw2     = (const float*)d_in[20];
    const float* cb2     = (const float*)d_in[21];
    const float* cw3     = (const float*)d_in[22];
    const float* cb3     = (const float*)d_in[23];

    int N = in_sizes[0] / 3;
    int E = in_sizes[2];
    float invN = 1.f / (float)N;

    char* ws = (char*)d_ws;
    float* A        = (float*)ws;                         ws += (size_t)N * HID * 4;
    float* B        = (float*)ws;                         ws += (size_t)N * HID * 4;
    float* ew       = (float*)ws;                         ws += (size_t)E * 4;
    int2*  csr      = (int2*)ws;                          ws += (size_t)E * 8;
    float* deg      = (float*)ws;                         ws += (size_t)N * 4;
    int*   cnt      = (int*)ws;                           ws += (size_t)N * 4;
    int*   row_ptr  = (int*)ws;                           ws += (size_t)(N + 1) * 4;
    int*   cursor   = (int*)ws;                           ws += (size_t)N * 4;
    float4* T3      = (float4*)ws;                        ws += (size_t)N * 16;
    float* gsum     = (float*)ws;                         ws += HID * 4;
    float* gbias    = (float*)ws;                         ws += HID * 4;

    float* out = (float*)d_out;  // [N] logits + [1] state value

    // --- edge MLP + degree + histogram
    hipMemsetAsync(deg, 0, (size_t)N * sizeof(float), stream);
    hipMemsetAsync(cnt, 0, (size_t)N * sizeof(int), stream);
    k_edge<<<(E + 255) / 256, 256, 0, stream>>>(eid, epos, id_emb, pos_emb,
                                                ew_w1, ew_b1, ew_w2, ew_b2, ei, ew, deg, cnt, E);
    k_dinv<<<(N + 255) / 256, 256, 0, stream>>>(deg, N);

    // --- CSR build
    k_scan<<<1, 1024, 0, stream>>>(cnt, row_ptr, cursor, N);
    k_fill<<<(E + 255) / 256, 256, 0, stream>>>(ei, ew, deg, cursor, csr, E);

    // --- layer 1: aggregate raw 3-float features, then expand through conv1_w
    k_agg3<<<(N + 255) / 256, 256, 0, stream>>>(row_ptr, csr, nf, deg, T3, N);
    k_x1<<<N, HID, 0, stream>>>(T3, c1w, c1b, B, N);  // B = x1

    // --- layer 2: aggregate x1 (linear), then GEMM with fused bias+relu
    k_gatherlin<<<(N + 3) / 4, 256, 0, stream>>>(row_ptr, csr, B, deg, A, N);  // A = agg(x1)
    k_gemm256<<<(N + 31) / 32, 256, 0, stream>>>(A, c2w, c2b, B, N);           // B = x2

    // --- pooling
    hipMemsetAsync(gsum, 0, HID * sizeof(float), stream);
    k_colsum<<<(N + 63) / 64, HID, 0, stream>>>(B, gsum, N);
    k_gbias<<<1, HID, 0, stream>>>(gsum, aw1, ab1, gbias, invN);

    // --- critic (writes out[N])
    k_critic<<<1, 2 * HID, 0, stream>>>(gsum, cw1, cb1, cw2, cb2, cw3, cb3, out + N, invN);

    // --- actor (writes out[0..N))
    k_actor<<<(N + 31) / 32, 256, 0, stream>>>(B, aw1, gbias, aw2, ab2, out, N);
}

// Round 5
// 654.892 us; speedup vs baseline: 9.0140x; 1.1359x over previous
//
#include <hip/hip_runtime.h>
#include <math.h>

#define HID 256

// ---------- edge weight MLP: ew = sigmoid(relu([id_emb|pos_emb] @ W1 + b1) @ W2 + b2)
// also accumulates deg[dst] += ew (float) and cnt[dst]++ (int) — both zeroed first
__global__ void k_edge(const int* __restrict__ eid, const int* __restrict__ epos,
                       const float* __restrict__ id_emb, const float* __restrict__ pos_emb,
                       const float* __restrict__ w1, const float* __restrict__ b1,
                       const float* __restrict__ w2, const float* __restrict__ b2,
                       const int* __restrict__ ei, float* __restrict__ ew,
                       float* __restrict__ deg, int* __restrict__ cnt, int E) {
    __shared__ float sW1[100];
    __shared__ float sB1[10];
    __shared__ float sW2[10];
    __shared__ float sB2;
    int t = threadIdx.x;
    if (t < 100) sW1[t] = w1[t];
    if (t < 10) { sB1[t] = b1[t]; sW2[t] = w2[t]; }
    if (t == 0) sB2 = b2[0];
    __syncthreads();
    int e = blockIdx.x * blockDim.x + t;
    if (e >= E) return;
    int id = eid[e];
    int p  = epos[e];
    const float4* ide = (const float4*)(id_emb + (size_t)id * 8);
    float4 fa = ide[0], fb = ide[1];
    float f[10];
    f[0] = fa.x; f[1] = fa.y; f[2] = fa.z; f[3] = fa.w;
    f[4] = fb.x; f[5] = fb.y; f[6] = fb.z; f[7] = fb.w;
    f[8] = pos_emb[p * 2 + 0];
    f[9] = pos_emb[p * 2 + 1];
    float acc = sB2;
#pragma unroll
    for (int j = 0; j < 10; j++) {
        float h = sB1[j];
#pragma unroll
        for (int i = 0; i < 10; i++) h += f[i] * sW1[i * 10 + j];
        h = fmaxf(h, 0.f);
        acc += h * sW2[j];
    }
    float w = 1.f / (1.f + expf(-acc));
    ew[e] = w;
    int dst = ei[E + e];
    atomicAdd(&deg[dst], w);
    atomicAdd(&cnt[dst], 1);
}

// ---------- dinv = 1/sqrt(deg+1) (in place) AND pack nf rows into float4
__global__ void k_dinv_pack(float* __restrict__ deg, const float* __restrict__ nf,
                            float4* __restrict__ nf4, int N) {
    int i = blockIdx.x * blockDim.x + threadIdx.x;
    if (i >= N) return;
    deg[i] = 1.f / sqrtf(deg[i] + 1.f);
    nf4[i] = make_float4(nf[i * 3 + 0], nf[i * 3 + 1], nf[i * 3 + 2], 0.f);
}

// ---------- exclusive prefix scan of cnt[N] -> row_ptr[N+1] AND cursor[N]
__global__ void k_scan(const int* __restrict__ cnt, int* __restrict__ row_ptr,
                       int* __restrict__ cursor, int N) {
    __shared__ int sums[1024];
    int t = threadIdx.x;
    int per = (N + 1023) / 1024;
    int start = t * per;
    int end = min(start + per, N);
    int s = 0;
    for (int i = start; i < end; i++) s += cnt[i];
    sums[t] = s;
    __syncthreads();
    for (int off = 1; off < 1024; off <<= 1) {
        int v = (t >= off) ? sums[t - off] : 0;
        __syncthreads();
        if (t >= off) sums[t] += v;
        __syncthreads();
    }
    int excl = (t == 0) ? 0 : sums[t - 1];
    for (int i = start; i < end; i++) {
        row_ptr[i] = excl;
        cursor[i] = excl;
        excl += cnt[i];
    }
    if (t == 1023) row_ptr[N] = excl;
}

// ---------- fill CSR: slot = cursor[dst]++; csr[slot] = {src, bitcast(norm)}
__global__ void k_fill(const int* __restrict__ ei, const float* __restrict__ ew,
                       const float* __restrict__ dinv, int* __restrict__ cursor,
                       int2* __restrict__ csr, int E) {
    int e = blockIdx.x * blockDim.x + threadIdx.x;
    if (e >= E) return;
    int src = ei[e];
    int dst = ei[E + e];
    int slot = atomicAdd(&cursor[dst], 1);
    float norm = dinv[src] * ew[e] * dinv[dst];
    csr[slot] = make_int2(src, __float_as_int(norm));
}

// ---------- layer-1 aggregation on RAW packed features, one thread per node
// T3[n] = sum_e norm*nf4[src] + dinv[n]^2 * nf4[n]
__global__ void k_agg3(const int* __restrict__ row_ptr, const int2* __restrict__ csr,
                       const float4* __restrict__ nf4, const float* __restrict__ dinv,
                       float4* __restrict__ T3, int N) {
    int n = blockIdx.x * blockDim.x + threadIdx.x;
    if (n >= N) return;
    int s = row_ptr[n];
    int e = row_ptr[n + 1];
    float ax = 0.f, ay = 0.f, az = 0.f;
    for (int i = s; i < e; i++) {
        int2 sn = csr[i];
        float w = __int_as_float(sn.y);
        float4 v = nf4[sn.x];
        ax = fmaf(w, v.x, ax);
        ay = fmaf(w, v.y, ay);
        az = fmaf(w, v.z, az);
    }
    float d = dinv[n];
    float dd = d * d;
    float4 v = nf4[n];
    ax = fmaf(dd, v.x, ax);
    ay = fmaf(dd, v.y, ay);
    az = fmaf(dd, v.z, az);
    T3[n] = make_float4(ax, ay, az, 0.f);
}

// ---------- fused layer-2 aggregation: recompute x1 on the fly from T3 (16B/node)
// A[n] = sum_e norm*relu(T3[src]@W1+b1) + dinv[n]^2*relu(T3[n]@W1+b1)
// one wave per node; lane holds cols 4*lane..4*lane+3 of W1/b1 in registers
__global__ void k_gatherfused(const int* __restrict__ row_ptr, const int2* __restrict__ csr,
                              const float4* __restrict__ T3, const float* __restrict__ dinv,
                              const float* __restrict__ cw, const float* __restrict__ cb,
                              float* __restrict__ A, int N) {
    int lane = threadIdx.x & 63;
    int wv = threadIdx.x >> 6;
    int n = blockIdx.x * 4 + wv;
    if (n >= N) return;
    const float4 w0 = *(const float4*)(cw + 4 * lane);            // W1 row 0
    const float4 w1 = *(const float4*)(cw + HID + 4 * lane);      // W1 row 1
    const float4 w2 = *(const float4*)(cw + 2 * HID + 4 * lane);  // W1 row 2
    const float4 bv = *(const float4*)(cb + 4 * lane);
    int s = row_ptr[n];
    int e = row_ptr[n + 1];
    float4 acc = make_float4(0.f, 0.f, 0.f, 0.f);
    for (int i = s; i < e; i++) {
        int2 sn = csr[i];
        float w = __int_as_float(sn.y);
        float4 t = T3[sn.x];
        float xx = fmaxf(fmaf(t.x, w0.x, fmaf(t.y, w1.x, fmaf(t.z, w2.x, bv.x))), 0.f);
        float xy = fmaxf(fmaf(t.x, w0.y, fmaf(t.y, w1.y, fmaf(t.z, w2.y, bv.y))), 0.f);
        float xz = fmaxf(fmaf(t.x, w0.z, fmaf(t.y, w1.z, fmaf(t.z, w2.z, bv.z))), 0.f);
        float xw = fmaxf(fmaf(t.x, w0.w, fmaf(t.y, w1.w, fmaf(t.z, w2.w, bv.w))), 0.f);
        acc.x = fmaf(w, xx, acc.x);
        acc.y = fmaf(w, xy, acc.y);
        acc.z = fmaf(w, xz, acc.z);
        acc.w = fmaf(w, xw, acc.w);
    }
    float d = dinv[n];
    float dd = d * d;
    float4 t = T3[n];
    float xx = fmaxf(fmaf(t.x, w0.x, fmaf(t.y, w1.x, fmaf(t.z, w2.x, bv.x))), 0.f);
    float xy = fmaxf(fmaf(t.x, w0.y, fmaf(t.y, w1.y, fmaf(t.z, w2.y, bv.y))), 0.f);
    float xz = fmaxf(fmaf(t.x, w0.z, fmaf(t.y, w1.z, fmaf(t.z, w2.z, bv.z))), 0.f);
    float xw = fmaxf(fmaf(t.x, w0.w, fmaf(t.y, w1.w, fmaf(t.z, w2.w, bv.w))), 0.f);
    acc.x = fmaf(dd, xx, acc.x);
    acc.y = fmaf(dd, xy, acc.y);
    acc.z = fmaf(dd, xz, acc.z);
    acc.w = fmaf(dd, xw, acc.w);
    *(float4*)(A + (size_t)n * HID + lane * 4) = acc;
}

// ================= register-tiled f32 GEMM with fused bias+relu AND column-sum epilogue:
// Y[N,256] = relu(X[N,256] @ W[256,256] + b);  gsum[c] += sum over block rows of Y
#define XS_STRIDE 36
__device__ __forceinline__ void gemm_tile_load(const float* __restrict__ X, float* xsT,
                                               int n0, int N, int tid) {
    int r = tid >> 3;        // 0..31
    int c8 = tid & 7;        // 0..7
    int n = n0 + r;
#pragma unroll
    for (int j = 0; j < 8; j++) {
        int c4 = c8 + 8 * j;  // 0..63
        float4 v = make_float4(0.f, 0.f, 0.f, 0.f);
        if (n < N) v = *(const float4*)(X + (size_t)n * HID + 4 * c4);
        int col = 4 * c4;
        xsT[(col + 0) * XS_STRIDE + r] = v.x;
        xsT[(col + 1) * XS_STRIDE + r] = v.y;
        xsT[(col + 2) * XS_STRIDE + r] = v.z;
        xsT[(col + 3) * XS_STRIDE + r] = v.w;
    }
}

__global__ __launch_bounds__(256) void k_gemm256(const float* __restrict__ X,
                                                 const float* __restrict__ W,
                                                 const float* __restrict__ b,
                                                 float* __restrict__ Y,
                                                 float* __restrict__ gsum, int N) {
    __shared__ __align__(16) float xsT[HID * XS_STRIDE];
    int tid = threadIdx.x;
    int n0 = blockIdx.x * 32;
    gemm_tile_load(X, xsT, n0, N, tid);
    __syncthreads();
    int tx = tid & 63;
    int ty = tid >> 6;
    float4 acc[8];
#pragma unroll
    for (int i = 0; i < 8; i++) acc[i] = make_float4(0.f, 0.f, 0.f, 0.f);
    const float* Wc = W + 4 * tx;
    const float* xbase = &xsT[ty * 8];
    for (int k = 0; k < HID; k++) {
        float4 w4 = *(const float4*)(Wc + (size_t)k * HID);
        const float* xp = xbase + k * XS_STRIDE;
        float4 xa = *(const float4*)xp;
        float4 xb = *(const float4*)(xp + 4);
        float xv[8];
        *(float4*)&xv[0] = xa;
        *(float4*)&xv[4] = xb;
#pragma unroll
        for (int i = 0; i < 8; i++) {
            acc[i].x = fmaf(xv[i], w4.x, acc[i].x);
            acc[i].y = fmaf(xv[i], w4.y, acc[i].y);
            acc[i].z = fmaf(xv[i], w4.z, acc[i].z);
            acc[i].w = fmaf(xv[i], w4.w, acc[i].w);
        }
    }
    float4 bv = *(const float4*)(b + 4 * tx);
    float4 csum = make_float4(0.f, 0.f, 0.f, 0.f);
#pragma unroll
    for (int i = 0; i < 8; i++) {
        int n = n0 + ty * 8 + i;
        if (n < N) {
            float4 o;
            o.x = fmaxf(acc[i].x + bv.x, 0.f);
            o.y = fmaxf(acc[i].y + bv.y, 0.f);
            o.z = fmaxf(acc[i].z + bv.z, 0.f);
            o.w = fmaxf(acc[i].w + bv.w, 0.f);
            *(float4*)(Y + (size_t)n * HID + 4 * tx) = o;
            csum.x += o.x; csum.y += o.y; csum.z += o.z; csum.w += o.w;
        }
    }
    // cross-wave column reduction in LDS (reuse xsT), then one atomic per column
    __syncthreads();
    float* sred = xsT;  // [4][HID]
    *(float4*)(sred + ty * HID + 4 * tx) = csum;
    __syncthreads();
    float s = sred[0 * HID + tid] + sred[1 * HID + tid] + sred[2 * HID + tid] + sred[3 * HID + tid];
    atomicAdd(&gsum[tid], s);
}

// ---------- actor fused: logits[n] = relu(x2[n] @ aw1_top + gbias) @ aw2 + ab2
__global__ __launch_bounds__(256) void k_actor(const float* __restrict__ X,
                                               const float* __restrict__ aw1,
                                               const float* __restrict__ gbias,
                                               const float* __restrict__ aw2,
                                               const float* __restrict__ ab2,
                                               float* __restrict__ out, int N) {
    __shared__ __align__(16) float xsT[HID * XS_STRIDE];
    int tid = threadIdx.x;
    int n0 = blockIdx.x * 32;
    gemm_tile_load(X, xsT, n0, N, tid);
    __syncthreads();
    int tx = tid & 63;
    int ty = tid >> 6;
    float4 acc[8];
#pragma unroll
    for (int i = 0; i < 8; i++) acc[i] = make_float4(0.f, 0.f, 0.f, 0.f);
    const float* Wc = aw1 + 4 * tx;
    const float* xbase = &xsT[ty * 8];
    for (int k = 0; k < HID; k++) {
        float4 w4 = *(const float4*)(Wc + (size_t)k * HID);
        const float* xp = xbase + k * XS_STRIDE;
        float4 xa = *(const float4*)xp;
        float4 xb = *(const float4*)(xp + 4);
        float xv[8];
        *(float4*)&xv[0] = xa;
        *(float4*)&xv[4] = xb;
#pragma unroll
        for (int i = 0; i < 8; i++) {
            acc[i].x = fmaf(xv[i], w4.x, acc[i].x);
            acc[i].y = fmaf(xv[i], w4.y, acc[i].y);
            acc[i].z = fmaf(xv[i], w4.z, acc[i].z);
            acc[i].w = fmaf(xv[i], w4.w, acc[i].w);
        }
    }
    float4 gb = *(const float4*)(gbias + 4 * tx);
    float4 w2 = *(const float4*)(aw2 + 4 * tx);
    float b2 = ab2[0];
#pragma unroll
    for (int i = 0; i < 8; i++) {
        float v = fmaxf(acc[i].x + gb.x, 0.f) * w2.x
                + fmaxf(acc[i].y + gb.y, 0.f) * w2.y
                + fmaxf(acc[i].z + gb.z, 0.f) * w2.z
                + fmaxf(acc[i].w + gb.w, 0.f) * w2.w;
#pragma unroll
        for (int off = 32; off > 0; off >>= 1) v += __shfl_down(v, off, 64);
        int n = n0 + ty * 8 + i;
        if (tx == 0 && n < N) out[n] = v + b2;
    }
}

// ---------- merged head prep: block 0 -> gbias, block 1 -> critic value
__global__ void k_heads(const float* __restrict__ gsum,
                        const float* __restrict__ aw1, const float* __restrict__ ab1,
                        float* __restrict__ gbias,
                        const float* __restrict__ cw1, const float* __restrict__ cb1,
                        const float* __restrict__ cw2, const float* __restrict__ cb2,
                        const float* __restrict__ cw3, const float* __restrict__ cb3,
                        float* __restrict__ sv_out, float invN) {
    int t = threadIdx.x;  // 512
    if (blockIdx.x == 0) {
        if (t < HID) {
            float s = ab1[t];
            for (int j = 0; j < HID; j++) s += gsum[j] * invN * aw1[(HID + j) * HID + t];
            gbias[t] = s;
        }
        return;
    }
    __shared__ float p[2 * HID];
    __shared__ float c1[2 * HID];
    __shared__ float c2[HID];
    p[t] = gsum[t & (HID - 1)] * invN;
    __syncthreads();
    float s = cb1[t];
    for (int i = 0; i < 2 * HID; i++) s += p[i] * cw1[i * 2 * HID + t];
    c1[t] = fmaxf(s, 0.f);
    __syncthreads();
    if (t < HID) {
        float s2 = cb2[t];
        for (int i = 0; i < 2 * HID; i++) s2 += c1[i] * cw2[i * HID + t];
        c2[t] = fmaxf(s2, 0.f) * cw3[t];
    }
    __syncthreads();
    for (int st = HID / 2; st > 0; st >>= 1) {
        if (t < st) c2[t] += c2[t + st];
        __syncthreads();
    }
    if (t == 0) sv_out[0] = c2[0] + cb3[0];
}

extern "C" void kernel_launch(void* const* d_in, const int* in_sizes, int n_in,
                              void* d_out, int out_size, void* d_ws, size_t ws_size,
                              hipStream_t stream) {
    const float* nf      = (const float*)d_in[0];
    const int*   ei      = (const int*)d_in[1];
    const int*   eid     = (const int*)d_in[2];
    const int*   epos    = (const int*)d_in[3];
    const float* id_emb  = (const float*)d_in[4];
    const float* pos_emb = (const float*)d_in[5];
    const float* ew_w1   = (const float*)d_in[6];
    const float* ew_b1   = (const float*)d_in[7];
    const float* ew_w2   = (const float*)d_in[8];
    const float* ew_b2   = (const float*)d_in[9];
    const float* c1w     = (const float*)d_in[10];
    const float* c1b     = (const float*)d_in[11];
    const float* c2w     = (const float*)d_in[12];
    const float* c2b     = (const float*)d_in[13];
    const float* aw1     = (const float*)d_in[14];
    const float* ab1     = (const float*)d_in[15];
    const float* aw2     = (const float*)d_in[16];
    const float* ab2     = (const float*)d_in[17];
    const float* cw1     = (const float*)d_in[18];
    const float* cb1     = (const float*)d_in[19];
    const float* cw2     = (const float*)d_in[20];
    const float* cb2     = (const float*)d_in[21];
    const float* cw3     = (const float*)d_in[22];
    const float* cb3     = (const float*)d_in[23];

    int N = in_sizes[0] / 3;
    int E = in_sizes[2];
    float invN = 1.f / (float)N;

    char* ws = (char*)d_ws;
    float* A        = (float*)ws;                         ws += (size_t)N * HID * 4;
    float* B        = (float*)ws;                         ws += (size_t)N * HID * 4;
    float* ew       = (float*)ws;                         ws += (size_t)E * 4;
    int2*  csr      = (int2*)ws;                          ws += (size_t)E * 8;
    float* deg      = (float*)ws;                         ws += (size_t)N * 4;
    int*   cnt      = (int*)ws;                           ws += (size_t)N * 4;
    int*   row_ptr  = (int*)ws;                           ws += (size_t)(N + 1) * 4;
    int*   cursor   = (int*)ws;                           ws += (size_t)N * 4;
    float4* T3      = (float4*)ws;                        ws += (size_t)N * 16;
    float4* nf4     = (float4*)ws;                        ws += (size_t)N * 16;
    float* gsum     = (float*)ws;                         ws += HID * 4;
    float* gbias    = (float*)ws;                         ws += HID * 4;

    float* out = (float*)d_out;  // [N] logits + [1] state value

    // --- edge MLP + degree + histogram
    hipMemsetAsync(deg, 0, (size_t)N * sizeof(float), stream);
    hipMemsetAsync(cnt, 0, (size_t)N * sizeof(int), stream);
    hipMemsetAsync(gsum, 0, HID * sizeof(float), stream);
    k_edge<<<(E + 255) / 256, 256, 0, stream>>>(eid, epos, id_emb, pos_emb,
                                                ew_w1, ew_b1, ew_w2, ew_b2, ei, ew, deg, cnt, E);
    k_dinv_pack<<<(N + 255) / 256, 256, 0, stream>>>(deg, nf, nf4, N);

    // --- CSR build
    k_scan<<<1, 1024, 0, stream>>>(cnt, row_ptr, cursor, N);
    k_fill<<<(E + 255) / 256, 256, 0, stream>>>(ei, ew, deg, cursor, csr, E);

    // --- layer 1 aggregate on raw features (16B/node)
    k_agg3<<<(N + 255) / 256, 256, 0, stream>>>(row_ptr, csr, nf4, deg, T3, N);

    // --- layer 2 aggregate with x1 recomputed on the fly; then GEMM (+bias+relu+colsum)
    k_gatherfused<<<(N + 3) / 4, 256, 0, stream>>>(row_ptr, csr, T3, deg, c1w, c1b, A, N);
    k_gemm256<<<(N + 31) / 32, 256, 0, stream>>>(A, c2w, c2b, B, gsum, N);  // B = x2

    // --- heads prep: gbias (block 0) + critic value (block 1, writes out[N])
    k_heads<<<2, 2 * HID, 0, stream>>>(gsum, aw1, ab1, gbias,
                                       cw1, cb1, cw2, cb2, cw3, cb3, out + N, invN);

    // --- actor (writes out[0..N))
    k_actor<<<(N + 31) / 32, 256, 0, stream>>>(B, aw1, gbias, aw2, ab2, out, N);
}

// Round 6
// 654.112 us; speedup vs baseline: 9.0247x; 1.0012x over previous
//
#include <hip/hip_runtime.h>
#include <math.h>

#define HID 256

// ---------- edge weight MLP: ew = sigmoid(relu([id_emb|pos_emb] @ W1 + b1) @ W2 + b2)
// also accumulates deg[dst] += ew (float) and cnt[dst]++ (int) — both zeroed first
__global__ void k_edge(const int* __restrict__ eid, const int* __restrict__ epos,
                       const float* __restrict__ id_emb, const float* __restrict__ pos_emb,
                       const float* __restrict__ w1, const float* __restrict__ b1,
                       const float* __restrict__ w2, const float* __restrict__ b2,
                       const int* __restrict__ ei, float* __restrict__ ew,
                       float* __restrict__ deg, int* __restrict__ cnt, int E) {
    __shared__ float sW1[100];
    __shared__ float sB1[10];
    __shared__ float sW2[10];
    __shared__ float sB2;
    int t = threadIdx.x;
    if (t < 100) sW1[t] = w1[t];
    if (t < 10) { sB1[t] = b1[t]; sW2[t] = w2[t]; }
    if (t == 0) sB2 = b2[0];
    __syncthreads();
    int e = blockIdx.x * blockDim.x + t;
    if (e >= E) return;
    int id = eid[e];
    int p  = epos[e];
    const float4* ide = (const float4*)(id_emb + (size_t)id * 8);
    float4 fa = ide[0], fb = ide[1];
    float f[10];
    f[0] = fa.x; f[1] = fa.y; f[2] = fa.z; f[3] = fa.w;
    f[4] = fb.x; f[5] = fb.y; f[6] = fb.z; f[7] = fb.w;
    f[8] = pos_emb[p * 2 + 0];
    f[9] = pos_emb[p * 2 + 1];
    float acc = sB2;
#pragma unroll
    for (int j = 0; j < 10; j++) {
        float h = sB1[j];
#pragma unroll
        for (int i = 0; i < 10; i++) h += f[i] * sW1[i * 10 + j];
        h = fmaxf(h, 0.f);
        acc += h * sW2[j];
    }
    float w = 1.f / (1.f + expf(-acc));
    ew[e] = w;
    int dst = ei[E + e];
    atomicAdd(&deg[dst], w);
    atomicAdd(&cnt[dst], 1);
}

// ---------- dinv = 1/sqrt(deg+1) (in place) AND pack nf rows into float4
__global__ void k_dinv_pack(float* __restrict__ deg, const float* __restrict__ nf,
                            float4* __restrict__ nf4, int N) {
    int i = blockIdx.x * blockDim.x + threadIdx.x;
    if (i >= N) return;
    deg[i] = 1.f / sqrtf(deg[i] + 1.f);
    nf4[i] = make_float4(nf[i * 3 + 0], nf[i * 3 + 1], nf[i * 3 + 2], 0.f);
}

// ---------- exclusive prefix scan of cnt[N] -> row_ptr[N+1] AND cursor[N]
__global__ void k_scan(const int* __restrict__ cnt, int* __restrict__ row_ptr,
                       int* __restrict__ cursor, int N) {
    __shared__ int sums[1024];
    int t = threadIdx.x;
    int per = (N + 1023) / 1024;
    int start = t * per;
    int end = min(start + per, N);
    int s = 0;
    for (int i = start; i < end; i++) s += cnt[i];
    sums[t] = s;
    __syncthreads();
    for (int off = 1; off < 1024; off <<= 1) {
        int v = (t >= off) ? sums[t - off] : 0;
        __syncthreads();
        if (t >= off) sums[t] += v;
        __syncthreads();
    }
    int excl = (t == 0) ? 0 : sums[t - 1];
    for (int i = start; i < end; i++) {
        row_ptr[i] = excl;
        cursor[i] = excl;
        excl += cnt[i];
    }
    if (t == 1023) row_ptr[N] = excl;
}

// ---------- fill CSR: slot = cursor[dst]++; csr[slot] = {src, bitcast(norm)}
__global__ void k_fill(const int* __restrict__ ei, const float* __restrict__ ew,
                       const float* __restrict__ dinv, int* __restrict__ cursor,
                       int2* __restrict__ csr, int E) {
    int e = blockIdx.x * blockDim.x + threadIdx.x;
    if (e >= E) return;
    int src = ei[e];
    int dst = ei[E + e];
    int slot = atomicAdd(&cursor[dst], 1);
    float norm = dinv[src] * ew[e] * dinv[dst];
    csr[slot] = make_int2(src, __float_as_int(norm));
}

// ---------- layer-1 aggregation on RAW packed features, one thread per node
__global__ void k_agg3(const int* __restrict__ row_ptr, const int2* __restrict__ csr,
                       const float4* __restrict__ nf4, const float* __restrict__ dinv,
                       float4* __restrict__ T3, int N) {
    int n = blockIdx.x * blockDim.x + threadIdx.x;
    if (n >= N) return;
    int s = row_ptr[n];
    int e = row_ptr[n + 1];
    float ax = 0.f, ay = 0.f, az = 0.f;
    for (int i = s; i < e; i++) {
        int2 sn = csr[i];
        float w = __int_as_float(sn.y);
        float4 v = nf4[sn.x];
        ax = fmaf(w, v.x, ax);
        ay = fmaf(w, v.y, ay);
        az = fmaf(w, v.z, az);
    }
    float d = dinv[n];
    float dd = d * d;
    float4 v = nf4[n];
    ax = fmaf(dd, v.x, ax);
    ay = fmaf(dd, v.y, ay);
    az = fmaf(dd, v.z, az);
    T3[n] = make_float4(ax, ay, az, 0.f);
}

// ---------- fused layer-2 aggregation: recompute x1 on the fly from T3 (16B/node)
__global__ void k_gatherfused(const int* __restrict__ row_ptr, const int2* __restrict__ csr,
                              const float4* __restrict__ T3, const float* __restrict__ dinv,
                              const float* __restrict__ cw, const float* __restrict__ cb,
                              float* __restrict__ A, int N) {
    int lane = threadIdx.x & 63;
    int wv = threadIdx.x >> 6;
    int n = blockIdx.x * 4 + wv;
    if (n >= N) return;
    const float4 w0 = *(const float4*)(cw + 4 * lane);
    const float4 w1 = *(const float4*)(cw + HID + 4 * lane);
    const float4 w2 = *(const float4*)(cw + 2 * HID + 4 * lane);
    const float4 bv = *(const float4*)(cb + 4 * lane);
    int s = row_ptr[n];
    int e = row_ptr[n + 1];
    float4 acc = make_float4(0.f, 0.f, 0.f, 0.f);
    for (int i = s; i < e; i++) {
        int2 sn = csr[i];
        float w = __int_as_float(sn.y);
        float4 t = T3[sn.x];
        float xx = fmaxf(fmaf(t.x, w0.x, fmaf(t.y, w1.x, fmaf(t.z, w2.x, bv.x))), 0.f);
        float xy = fmaxf(fmaf(t.x, w0.y, fmaf(t.y, w1.y, fmaf(t.z, w2.y, bv.y))), 0.f);
        float xz = fmaxf(fmaf(t.x, w0.z, fmaf(t.y, w1.z, fmaf(t.z, w2.z, bv.z))), 0.f);
        float xw = fmaxf(fmaf(t.x, w0.w, fmaf(t.y, w1.w, fmaf(t.z, w2.w, bv.w))), 0.f);
        acc.x = fmaf(w, xx, acc.x);
        acc.y = fmaf(w, xy, acc.y);
        acc.z = fmaf(w, xz, acc.z);
        acc.w = fmaf(w, xw, acc.w);
    }
    float d = dinv[n];
    float dd = d * d;
    float4 t = T3[n];
    float xx = fmaxf(fmaf(t.x, w0.x, fmaf(t.y, w1.x, fmaf(t.z, w2.x, bv.x))), 0.f);
    float xy = fmaxf(fmaf(t.x, w0.y, fmaf(t.y, w1.y, fmaf(t.z, w2.y, bv.y))), 0.f);
    float xz = fmaxf(fmaf(t.x, w0.z, fmaf(t.y, w1.z, fmaf(t.z, w2.z, bv.z))), 0.f);
    float xw = fmaxf(fmaf(t.x, w0.w, fmaf(t.y, w1.w, fmaf(t.z, w2.w, bv.w))), 0.f);
    acc.x = fmaf(dd, xx, acc.x);
    acc.y = fmaf(dd, xy, acc.y);
    acc.z = fmaf(dd, xz, acc.z);
    acc.w = fmaf(dd, xw, acc.w);
    *(float4*)(A + (size_t)n * HID + lane * 4) = acc;
}

// ================= fused double GEMM:
// phase 1: x2 = relu(A @ W2 + b2)   (32-row tile, regs)
// epilogue: gsum += colsum(x2)      (LDS cross-wave reduce + 1 atomic/thread)
// phase 2: P = x2 @ aw1_top         (x2 via LDS row-major broadcast)
// x2 never touches global memory.
#define XS_STRIDE 36
#define X2_STRIDE 260

__global__ __launch_bounds__(256, 4) void k_gemm_fused(
        const float* __restrict__ A, const float* __restrict__ W2,
        const float* __restrict__ b2, const float* __restrict__ aw1,
        float* __restrict__ P, float* __restrict__ gsum, int N) {
    __shared__ __align__(16) float smem[HID * XS_STRIDE];   // 36 KB: xsT then x2s
    __shared__ __align__(16) float sred[4 * HID];           // 4 KB colsum reduce
    int tid = threadIdx.x;
    int n0 = blockIdx.x * 32;

    // --- stage A tile transposed: xsT[col*36 + r]
    {
        int r = tid >> 3;
        int c8 = tid & 7;
        int n = n0 + r;
#pragma unroll
        for (int j = 0; j < 8; j++) {
            int c4 = c8 + 8 * j;
            float4 v = make_float4(0.f, 0.f, 0.f, 0.f);
            if (n < N) v = *(const float4*)(A + (size_t)n * HID + 4 * c4);
            int col = 4 * c4;
            smem[(col + 0) * XS_STRIDE + r] = v.x;
            smem[(col + 1) * XS_STRIDE + r] = v.y;
            smem[(col + 2) * XS_STRIDE + r] = v.z;
            smem[(col + 3) * XS_STRIDE + r] = v.w;
        }
    }
    __syncthreads();

    int tx = tid & 63;
    int ty = tid >> 6;

    // --- phase 1: x2 tile = relu(A@W2 + b2), unroll k by 8 with batched W loads
    float4 acc[8];
#pragma unroll
    for (int i = 0; i < 8; i++) acc[i] = make_float4(0.f, 0.f, 0.f, 0.f);
    {
        const float* Wc = W2 + 4 * tx;
        const float* xbase = &smem[ty * 8];
        for (int k0 = 0; k0 < HID; k0 += 8) {
            float4 w[8];
#pragma unroll
            for (int j = 0; j < 8; j++) w[j] = *(const float4*)(Wc + (size_t)(k0 + j) * HID);
#pragma unroll
            for (int j = 0; j < 8; j++) {
                const float* xp = xbase + (k0 + j) * XS_STRIDE;
                float4 xa = *(const float4*)xp;
                float4 xb = *(const float4*)(xp + 4);
                float xv[8];
                *(float4*)&xv[0] = xa;
                *(float4*)&xv[4] = xb;
#pragma unroll
                for (int i = 0; i < 8; i++) {
                    acc[i].x = fmaf(xv[i], w[j].x, acc[i].x);
                    acc[i].y = fmaf(xv[i], w[j].y, acc[i].y);
                    acc[i].z = fmaf(xv[i], w[j].z, acc[i].z);
                    acc[i].w = fmaf(xv[i], w[j].w, acc[i].w);
                }
            }
        }
    }
    float4 bv = *(const float4*)(b2 + 4 * tx);
#pragma unroll
    for (int i = 0; i < 8; i++) {
        acc[i].x = fmaxf(acc[i].x + bv.x, 0.f);
        acc[i].y = fmaxf(acc[i].y + bv.y, 0.f);
        acc[i].z = fmaxf(acc[i].z + bv.z, 0.f);
        acc[i].w = fmaxf(acc[i].w + bv.w, 0.f);
    }
    __syncthreads();  // done reading xsT

    // --- write x2 tile to LDS row-major x2s[r*260 + c], and colsum (valid rows only)
    float4 csum = make_float4(0.f, 0.f, 0.f, 0.f);
#pragma unroll
    for (int i = 0; i < 8; i++) {
        int r = ty * 8 + i;
        *(float4*)(smem + r * X2_STRIDE + 4 * tx) = acc[i];
        if (n0 + r < N) {
            csum.x += acc[i].x; csum.y += acc[i].y;
            csum.z += acc[i].z; csum.w += acc[i].w;
        }
    }
    *(float4*)(sred + ty * HID + 4 * tx) = csum;
    __syncthreads();
    {
        float s = sred[0 * HID + tid] + sred[1 * HID + tid]
                + sred[2 * HID + tid] + sred[3 * HID + tid];
        atomicAdd(&gsum[tid], s);
    }

    // --- phase 2: P = x2 @ aw1_top, unroll k by 4 (b128 broadcast reads of x2)
    float4 acc2[8];
#pragma unroll
    for (int i = 0; i < 8; i++) acc2[i] = make_float4(0.f, 0.f, 0.f, 0.f);
    {
        const float* Wc = aw1 + 4 * tx;
        const float* xbase = smem + (ty * 8) * X2_STRIDE;
        for (int k0 = 0; k0 < HID; k0 += 4) {
            float4 w[4];
#pragma unroll
            for (int j = 0; j < 4; j++) w[j] = *(const float4*)(Wc + (size_t)(k0 + j) * HID);
            float4 xr[8];
#pragma unroll
            for (int i = 0; i < 8; i++) xr[i] = *(const float4*)(xbase + i * X2_STRIDE + k0);
#pragma unroll
            for (int i = 0; i < 8; i++) {
                acc2[i].x = fmaf(xr[i].x, w[0].x, acc2[i].x);
                acc2[i].y = fmaf(xr[i].x, w[0].y, acc2[i].y);
                acc2[i].z = fmaf(xr[i].x, w[0].z, acc2[i].z);
                acc2[i].w = fmaf(xr[i].x, w[0].w, acc2[i].w);
                acc2[i].x = fmaf(xr[i].y, w[1].x, acc2[i].x);
                acc2[i].y = fmaf(xr[i].y, w[1].y, acc2[i].y);
                acc2[i].z = fmaf(xr[i].y, w[1].z, acc2[i].z);
                acc2[i].w = fmaf(xr[i].y, w[1].w, acc2[i].w);
                acc2[i].x = fmaf(xr[i].z, w[2].x, acc2[i].x);
                acc2[i].y = fmaf(xr[i].z, w[2].y, acc2[i].y);
                acc2[i].z = fmaf(xr[i].z, w[2].z, acc2[i].z);
                acc2[i].w = fmaf(xr[i].z, w[2].w, acc2[i].w);
                acc2[i].x = fmaf(xr[i].w, w[3].x, acc2[i].x);
                acc2[i].y = fmaf(xr[i].w, w[3].y, acc2[i].y);
                acc2[i].z = fmaf(xr[i].w, w[3].z, acc2[i].z);
                acc2[i].w = fmaf(xr[i].w, w[3].w, acc2[i].w);
            }
        }
    }
#pragma unroll
    for (int i = 0; i < 8; i++) {
        int n = n0 + ty * 8 + i;
        if (n < N) *(float4*)(P + (size_t)n * HID + 4 * tx) = acc2[i];
    }
}

// ---------- logits epilogue: out[n] = relu(P[n,:] + gbias) @ aw2 + ab2
__global__ void k_logits(const float* __restrict__ P, const float* __restrict__ gbias,
                         const float* __restrict__ aw2, const float* __restrict__ ab2,
                         float* __restrict__ out, int N) {
    int lane = threadIdx.x & 63;
    int wv = threadIdx.x >> 6;
    int n = blockIdx.x * 4 + wv;
    if (n >= N) return;
    float4 p = *(const float4*)(P + (size_t)n * HID + 4 * lane);
    float4 gb = *(const float4*)(gbias + 4 * lane);
    float4 w2 = *(const float4*)(aw2 + 4 * lane);
    float v = fmaxf(p.x + gb.x, 0.f) * w2.x
            + fmaxf(p.y + gb.y, 0.f) * w2.y
            + fmaxf(p.z + gb.z, 0.f) * w2.z
            + fmaxf(p.w + gb.w, 0.f) * w2.w;
#pragma unroll
    for (int off = 32; off > 0; off >>= 1) v += __shfl_down(v, off, 64);
    if (lane == 0) out[n] = v + ab2[0];
}

// ---------- merged head prep: block 0 -> gbias, block 1 -> critic value
__global__ void k_heads(const float* __restrict__ gsum,
                        const float* __restrict__ aw1, const float* __restrict__ ab1,
                        float* __restrict__ gbias,
                        const float* __restrict__ cw1, const float* __restrict__ cb1,
                        const float* __restrict__ cw2, const float* __restrict__ cb2,
                        const float* __restrict__ cw3, const float* __restrict__ cb3,
                        float* __restrict__ sv_out, float invN) {
    int t = threadIdx.x;  // 512
    if (blockIdx.x == 0) {
        if (t < HID) {
            float s = ab1[t];
            for (int j = 0; j < HID; j++) s += gsum[j] * invN * aw1[(HID + j) * HID + t];
            gbias[t] = s;
        }
        return;
    }
    __shared__ float p[2 * HID];
    __shared__ float c1[2 * HID];
    __shared__ float c2[HID];
    p[t] = gsum[t & (HID - 1)] * invN;
    __syncthreads();
    float s = cb1[t];
    for (int i = 0; i < 2 * HID; i++) s += p[i] * cw1[i * 2 * HID + t];
    c1[t] = fmaxf(s, 0.f);
    __syncthreads();
    if (t < HID) {
        float s2 = cb2[t];
        for (int i = 0; i < 2 * HID; i++) s2 += c1[i] * cw2[i * HID + t];
        c2[t] = fmaxf(s2, 0.f) * cw3[t];
    }
    __syncthreads();
    for (int st = HID / 2; st > 0; st >>= 1) {
        if (t < st) c2[t] += c2[t + st];
        __syncthreads();
    }
    if (t == 0) sv_out[0] = c2[0] + cb3[0];
}

extern "C" void kernel_launch(void* const* d_in, const int* in_sizes, int n_in,
                              void* d_out, int out_size, void* d_ws, size_t ws_size,
                              hipStream_t stream) {
    const float* nf      = (const float*)d_in[0];
    const int*   ei      = (const int*)d_in[1];
    const int*   eid     = (const int*)d_in[2];
    const int*   epos    = (const int*)d_in[3];
    const float* id_emb  = (const float*)d_in[4];
    const float* pos_emb = (const float*)d_in[5];
    const float* ew_w1   = (const float*)d_in[6];
    const float* ew_b1   = (const float*)d_in[7];
    const float* ew_w2   = (const float*)d_in[8];
    const float* ew_b2   = (const float*)d_in[9];
    const float* c1w     = (const float*)d_in[10];
    const float* c1b     = (const float*)d_in[11];
    const float* c2w     = (const float*)d_in[12];
    const float* c2b     = (const float*)d_in[13];
    const float* aw1     = (const float*)d_in[14];
    const float* ab1     = (const float*)d_in[15];
    const float* aw2     = (const float*)d_in[16];
    const float* ab2     = (const float*)d_in[17];
    const float* cw1     = (const float*)d_in[18];
    const float* cb1     = (const float*)d_in[19];
    const float* cw2     = (const float*)d_in[20];
    const float* cb2     = (const float*)d_in[21];
    const float* cw3     = (const float*)d_in[22];
    const float* cb3     = (const float*)d_in[23];

    int N = in_sizes[0] / 3;
    int E = in_sizes[2];
    float invN = 1.f / (float)N;

    char* ws = (char*)d_ws;
    float* A        = (float*)ws;                         ws += (size_t)N * HID * 4;
    float* P        = (float*)ws;                         ws += (size_t)N * HID * 4;
    float* ew       = (float*)ws;                         ws += (size_t)E * 4;
    int2*  csr      = (int2*)ws;                          ws += (size_t)E * 8;
    float* deg      = (float*)ws;                         ws += (size_t)N * 4;
    int*   cnt      = (int*)ws;                           ws += (size_t)N * 4;
    int*   row_ptr  = (int*)ws;                           ws += (size_t)(N + 1) * 4;
    int*   cursor   = (int*)ws;                           ws += (size_t)N * 4;
    float4* T3      = (float4*)ws;                        ws += (size_t)N * 16;
    float4* nf4     = (float4*)ws;                        ws += (size_t)N * 16;
    float* gsum     = (float*)ws;                         ws += HID * 4;
    float* gbias    = (float*)ws;                         ws += HID * 4;

    float* out = (float*)d_out;  // [N] logits + [1] state value

    // --- edge MLP + degree + histogram
    hipMemsetAsync(deg, 0, (size_t)N * sizeof(float), stream);
    hipMemsetAsync(cnt, 0, (size_t)N * sizeof(int), stream);
    hipMemsetAsync(gsum, 0, HID * sizeof(float), stream);
    k_edge<<<(E + 255) / 256, 256, 0, stream>>>(eid, epos, id_emb, pos_emb,
                                                ew_w1, ew_b1, ew_w2, ew_b2, ei, ew, deg, cnt, E);
    k_dinv_pack<<<(N + 255) / 256, 256, 0, stream>>>(deg, nf, nf4, N);

    // --- CSR build
    k_scan<<<1, 1024, 0, stream>>>(cnt, row_ptr, cursor, N);
    k_fill<<<(E + 255) / 256, 256, 0, stream>>>(ei, ew, deg, cursor, csr, E);

    // --- layer 1 aggregate on raw features (16B/node)
    k_agg3<<<(N + 255) / 256, 256, 0, stream>>>(row_ptr, csr, nf4, deg, T3, N);

    // --- layer 2 aggregate with x1 recomputed on the fly
    k_gatherfused<<<(N + 3) / 4, 256, 0, stream>>>(row_ptr, csr, T3, deg, c1w, c1b, A, N);

    // --- fused conv2-GEMM + actor-GEMM (+ colsum); x2 stays on-chip
    k_gemm_fused<<<(N + 31) / 32, 256, 0, stream>>>(A, c2w, c2b, aw1, P, gsum, N);

    // --- heads prep: gbias (block 0) + critic value (block 1, writes out[N])
    k_heads<<<2, 2 * HID, 0, stream>>>(gsum, aw1, ab1, gbias,
                                       cw1, cb1, cw2, cb2, cw3, cb3, out + N, invN);

    // --- logits epilogue (writes out[0..N))
    k_logits<<<(N + 3) / 4, 256, 0, stream>>>(P, gbias, aw2, ab2, out, N);
}